// Round 18
// baseline (538.578 us; speedup 1.0000x reference)
//
#include <hip/hip_runtime.h>
#include <hip/hip_bf16.h>

// ---------------- types ----------------
typedef __bf16 bfrag  __attribute__((ext_vector_type(8)));  // 8 bf16 = 4 VGPR (MFMA A/B frag)
typedef __bf16 bf16x4 __attribute__((ext_vector_type(4)));
typedef float  f32x4  __attribute__((ext_vector_type(4)));

#define MFMA(a,b,c) __builtin_amdgcn_mfma_f32_16x16x32_bf16(a,b,c,0,0,0)

__device__ __forceinline__ void gl_lds16(const void* g, void* l) {
  __builtin_amdgcn_global_load_lds((const __attribute__((address_space(1))) void*)g,
                                   (__attribute__((address_space(3))) void*)l, 16, 0, 0);
}
// raw 2^x (inputs are small/normal here; avoids OCML guard path)
__device__ __forceinline__ float fexp2(float x) {
  float r;
  asm("v_exp_f32 %0, %1" : "=v"(r) : "v"(x));
  return r;
}
// pack two f32 -> (bf16,bf16) in one u32
__device__ __forceinline__ unsigned cvtpk(float lo, float hi) {
  unsigned r;
  asm("v_cvt_pk_bf16_f32 %0, %1, %2" : "=v"(r) : "v"(lo), "v"(hi));
  return r;
}

// ---------------- problem dims ----------------
// B=4 S=2048 DIM=768 H=12 HD=64 QK=32 R=8
// C (proj out) cols: q[0,768) k[768,1536) v[1536,2048) qv[2048,2432)
#define NC 2432

// ---------------- workspace layout (bytes) ----------------
#define OFF_C     ((size_t)0)           // bf16 [8192][2432]    39,845,888
#define OFF_VT    ((size_t)52428800)    // bf16 [4][528][2048]   8,650,752  (rows 512-519=vw; 520-527 garbage, feeds discarded MFMA cols)
#define OFF_QDOT  ((size_t)61079552)    // f32  [4][2048][12]      393,216
#define OFF_WCAT  ((size_t)61472768)    // bf16 [2432][768]      3,735,552
#define OFF_BCAT  ((size_t)65208320)    // f32  [2432]               9,728
#define OFF_WFT   ((size_t)65218048)    // bf16 [768][768]       1,179,648
#define OFF_W1T   ((size_t)66397696)    // bf16 [1536][768]      2,359,296
#define OFF_W2T   ((size_t)68756992)    // bf16 [768][1536]      2,359,296
#define OFF_ATTNO ((size_t)71116288)    // bf16 [8192][768]     12,582,912
#define OFF_XN    ((size_t)39845888)    // bf16 [8192][768]     12,582,912
// reuse (after attention, C/XN/VT dead):
#define OFF_OUT1  ((size_t)0)           // bf16 [8192][768]
#define OFF_ON    ((size_t)12582912)    // bf16 [8192][768]
#define OFF_H1    ((size_t)25165824)    // bf16 [8192][1536]

// ---------------- LayerNorm: wave per row (768 cols) ----------------
template<typename TIN>
__global__ __launch_bounds__(256) void k_ln(const TIN* __restrict__ in,
    const float* __restrict__ g, const float* __restrict__ be, __bf16* __restrict__ out) {
  int row  = blockIdx.x * 4 + (threadIdx.x >> 6);
  int lane = threadIdx.x & 63;
  const TIN* rp = in + (size_t)row * 768;
  float v[12];
  #pragma unroll
  for (int i = 0; i < 3; i++) {
    int c = i * 256 + lane * 4;
    if constexpr (sizeof(TIN) == 4) {
      float4 lv = *(const float4*)(rp + c);
      v[i*4+0] = lv.x; v[i*4+1] = lv.y; v[i*4+2] = lv.z; v[i*4+3] = lv.w;
    } else {
      bf16x4 lv = *(const bf16x4*)(rp + c);
      #pragma unroll
      for (int jj = 0; jj < 4; jj++) v[i*4+jj] = (float)lv[jj];
    }
  }
  float s = 0.f, sq = 0.f;
  #pragma unroll
  for (int k = 0; k < 12; k++) { s += v[k]; sq += v[k]*v[k]; }
  #pragma unroll
  for (int d = 1; d < 64; d <<= 1) { s += __shfl_xor(s, d); sq += __shfl_xor(sq, d); }
  float mean = s * (1.f/768.f);
  float rstd = rsqrtf(sq * (1.f/768.f) - mean*mean + 1e-5f);
  #pragma unroll
  for (int i = 0; i < 3; i++) {
    int c = i * 256 + lane * 4;
    float4 gv = *(const float4*)(g + c);
    float4 bv = *(const float4*)(be + c);
    bf16x4 o;
    o[0] = (__bf16)((v[i*4+0]-mean)*rstd*gv.x + bv.x);
    o[1] = (__bf16)((v[i*4+1]-mean)*rstd*gv.y + bv.y);
    o[2] = (__bf16)((v[i*4+2]-mean)*rstd*gv.z + bv.z);
    o[3] = (__bf16)((v[i*4+3]-mean)*rstd*gv.w + bv.w);
    *(bf16x4*)(out + (size_t)row*768 + c) = o;
  }
}

// ---------------- pack W (transpose f32->bf16, K-major) ----------------
__global__ __launch_bounds__(256) void k_packT(const float* __restrict__ src, __bf16* __restrict__ dst,
                                               int N, int K, int total) {
  int idx = blockIdx.x * 256 + threadIdx.x;
  if (idx >= total) return;
  int K8 = K >> 3;
  int n = idx / K8, k0 = (idx % K8) * 8;
  bfrag o;
  #pragma unroll
  for (int i = 0; i < 8; i++) o[i] = (__bf16)src[(size_t)(k0+i)*N + n];
  *(bfrag*)&dst[(size_t)n*K + k0] = o;
}

__global__ __launch_bounds__(256) void k_packcat(
    const float* __restrict__ Wq, const float* __restrict__ Wk,
    const float* __restrict__ Wv, const float* __restrict__ Wqv,
    const float* __restrict__ bq, const float* __restrict__ bk,
    const float* __restrict__ bv, const float* __restrict__ bqv,
    __bf16* __restrict__ Wt, float* __restrict__ bcat) {
  int idx = blockIdx.x * 256 + threadIdx.x;
  if (idx >= 2432 * 96) return;
  int n = idx / 96, k0 = (idx % 96) * 8;
  const float* src; int col, sN; float sc = 1.f;
  if (n < 768)       { src = Wq;  col = n;        sN = 768; sc = 0.125f; }            // 1/sqrt(64)
  else if (n < 1536) { src = Wk;  col = n - 768;  sN = 768; }
  else if (n < 2048) { src = Wv;  col = n - 1536; sN = 512; }
  else               { src = Wqv; col = n - 2048; sN = 384; sc = 0.1767766952966369f; } // 1/sqrt(32)
  bfrag o;
  #pragma unroll
  for (int i = 0; i < 8; i++) o[i] = (__bf16)(src[(size_t)(k0+i)*sN + col] * sc);
  *(bfrag*)&Wt[(size_t)n*768 + k0] = o;
  if (k0 == 0) {
    float bb;
    if (n < 768) bb = bq[col]*0.125f;
    else if (n < 1536) bb = bk[col];
    else if (n < 2048) bb = bv[col];
    else bb = bqv[col]*0.1767766952966369f;
    bcat[n] = bb;
  }
}

// ---------------- GEMM: [8192,KD]bf16 @ Bt[N,KD]bf16 -> epilogues ----------------
template<int KD, int EPI>
__global__ __launch_bounds__(256, 3) void k_gemm(const __bf16* __restrict__ A,
    const __bf16* __restrict__ Bt, const float* __restrict__ bias,
    const float* __restrict__ resf, const __bf16* __restrict__ resb,
    void* __restrict__ Cout, int N) {
  __shared__ __bf16 Al[2][128*32];
  __shared__ __bf16 Bl[2][128*32];
  // bijective XCD swizzle on m-tiles (gridDim.x == 64 == 8*8)
  const int bx = (blockIdx.x & 7) * 8 + (blockIdx.x >> 3);
  const int m0 = bx * 128, n0 = blockIdx.y * 128;
  const int tid = threadIdx.x, lane = tid & 63, w = tid >> 6;
  const int wm = (w >> 1) * 64, wn = (w & 1) * 64;
  const int srow = lane >> 2, skoff = (lane & 3) * 8;
  const int l15 = lane & 15, lg = lane >> 4;
  f32x4 acc[4][4];
  #pragma unroll
  for (int i = 0; i < 4; i++)
    #pragma unroll
    for (int j = 0; j < 4; j++) acc[i][j] = (f32x4){0.f,0.f,0.f,0.f};
  const int NT = KD / 32;
  auto stage = [&](int buf, int k0) {
    #pragma unroll
    for (int i = 0; i < 2; i++) {
      int c = w * 2 + i;
      gl_lds16(A  + (size_t)(m0 + c*16 + srow) * KD + k0 + skoff, &Al[buf][c*512]);
      gl_lds16(Bt + (size_t)(n0 + c*16 + srow) * KD + k0 + skoff, &Bl[buf][c*512]);
    }
  };
  stage(0, 0);
  __syncthreads();
  for (int t = 0; t < NT; t++) {
    int buf = t & 1;
    if (t + 1 < NT) stage(buf ^ 1, (t + 1) * 32);
    bfrag af[4], bfm[4];
    #pragma unroll
    for (int f = 0; f < 4; f++) {
      af[f]  = *(const bfrag*)&Al[buf][(wm + f*16 + l15)*32 + lg*8];
      bfm[f] = *(const bfrag*)&Bl[buf][(wn + f*16 + l15)*32 + lg*8];
    }
    #pragma unroll
    for (int i = 0; i < 4; i++)
      #pragma unroll
      for (int j = 0; j < 4; j++)
        acc[i][j] = MFMA(af[i], bfm[j], acc[i][j]);
    __syncthreads();
  }
  #pragma unroll
  for (int i = 0; i < 4; i++) {
    int row0 = m0 + wm + i*16 + lg*4;
    #pragma unroll
    for (int j = 0; j < 4; j++) {
      int col = n0 + wn + j*16 + l15;
      float bv = bias[col];
      #pragma unroll
      for (int q = 0; q < 4; q++) {
        size_t r = (size_t)(row0 + q);
        float v = acc[i][j][q] + bv;
        if (EPI == 0)      ((__bf16*)Cout)[r*N + col] = (__bf16)v;
        else if (EPI == 1) { v += resf[r*N + col]; ((__bf16*)Cout)[r*N + col] = (__bf16)v; }
        else if (EPI == 2) ((__bf16*)Cout)[r*N + col] = (__bf16)fmaxf(v, 0.f);
        else               { v += (float)resb[r*N + col]; ((float*)Cout)[r*N + col] = v; }
      }
    }
  }
}

// ---------------- V transpose + vw: VT[b][d][k] = C[..][1536+d]; vw fused ----------------
__global__ __launch_bounds__(256) void k_vt(const __bf16* __restrict__ C, const float* __restrict__ Ws,
                                            __bf16* __restrict__ VT) {
  int bid = blockIdx.x;
  int b = bid >> 8, dt = (bid >> 5) & 7, kt = bid & 31;
  __shared__ __bf16 tile[64][72];
  int tid = threadIdx.x;
  int r = tid >> 3, c0 = (tid & 7) * 8;
  #pragma unroll
  for (int p = 0; p < 2; p++) {
    int rr = r + p * 32;
    bfrag v = *(const bfrag*)&C[(size_t)(b*2048 + kt*64 + rr)*NC + 1536 + dt*64 + c0];
    *(bfrag*)&tile[rr][c0] = v;
  }
  __syncthreads();
  #pragma unroll
  for (int p = 0; p < 2; p++) {
    int d = r + p * 32;
    bfrag o;
    #pragma unroll
    for (int i = 0; i < 8; i++) o[i] = tile[c0 + i][d];
    *(bfrag*)&VT[((size_t)b*528 + dt*64 + d)*2048 + kt*64 + c0] = o;
  }
  // vw row for r=dt: 64 threads each sum one k-row over d=0..64
  if (tid < 64) {
    float s = 0.f;
    #pragma unroll
    for (int d = 0; d < 64; d++) s += (float)tile[tid][d] * Ws[32 + d];
    VT[((size_t)b*528 + 512 + dt)*2048 + kt*64 + tid] = (__bf16)s;
  }
}

// ---------------- qdot: qv . ws_q + bs ----------------
__global__ __launch_bounds__(256) void k_qdot(const __bf16* __restrict__ C, const float* __restrict__ Ws,
                                              const float* __restrict__ bs, float* __restrict__ qd) {
  int idx = blockIdx.x * 256 + threadIdx.x;
  if (idx >= 98304) return;
  int h = idx % 12; size_t srow = (size_t)(idx / 12);
  const __bf16* qp = &C[srow*NC + 2048 + h*32];
  float s = bs[0];
  #pragma unroll
  for (int j = 0; j < 32; j++) s += (float)qp[j] * Ws[j];
  qd[idx] = s;
}

// ---------------- fused flash attention + compositional mixing ----------------
// R18: R17 + intra-wave pipe interleave. qk_phase split into qk_mfma (scores ->
// regs) and qk_finish (exp/pack/P-write). Loop body: qk_mfma(t+1) -> comp(t) ->
// PV rf0-3 -> qk_finish(t+1) -> PV rf4-7, so the softmax VALU block sits
// between MFMA clusters inside one barrier region (Pl buffers pb vs pb^1 are
// disjoint). s[] extends liveness by 16 VGPR (~276/wave, well under the
// single-resident-block 512 cap).
// LDS map (loop):
//   [0,32768)      Pl dbuf [2][128][128B swizzled]
//   [32768,49152)  kbuf dbuf [2][8192B]
//   [49152,53248)  wlb [128][8] f32
// Epilogue: rbuf [8][32][64]bf16 (32KB) overlaps Pl; 4 static chunks of 32 rows.
__global__ __launch_bounds__(512, 2) void k_attn(const __bf16* __restrict__ C,
    const __bf16* __restrict__ VT,
    const float* __restrict__ qdot, __bf16* __restrict__ attno, float* __restrict__ prevout) {
  __shared__ __align__(16) char smem[53248];
  __bf16* Pl   = (__bf16*)(smem);
  __bf16* kbuf = (__bf16*)(smem + 32768);
  float*  wlb  = (float*)(smem + 49152);
  __bf16* rbuf = (__bf16*)(smem);

  const int tid = threadIdx.x, lane = tid & 63, wid = tid >> 6;
  const int l15 = lane & 15, lg = lane >> 4;
  // bijective XCD swizzle: 768 = 8 * 96
  const int bid = (blockIdx.x & 7) * 96 + (blockIdx.x >> 3);
  const int b = bid / 192, rem = bid % 192, h = rem / 16, qb = rem % 16;
  const int q0 = qb * 128;

  const __bf16* VTb = VT + (size_t)b * 528 * 2048;
  // per-lane pre-swizzled K source in C: thread (key=tid>>3, ch=tid&7) loads
  // K[key][(ch^(key&7))*8 ..+8] of tile 0; tile t adds t*64 rows
  const int kkey = tid >> 3, kch = tid & 7;
  const __bf16* Ksrc0 = C + (size_t)(b*2048 + kkey)*NC + 768 + h*64 + ((kch ^ (kkey & 7)) * 8);

  auto stageK = [&](int t) {
    gl_lds16(Ksrc0 + (size_t)t * 64 * NC, kbuf + (t & 1)*4096 + (size_t)wid*512);
  };
  stageK(0);

  const __bf16* Qbase = C + (size_t)(b*2048 + q0 + wid*16 + l15)*NC + h*64 + lg*8;
  bfrag qf0 = *(const bfrag*)(Qbase);
  bfrag qf1 = *(const bfrag*)(Qbase + 32);

  f32x4 accv[8][4];
  #pragma unroll
  for (int i = 0; i < 8; i++)
    #pragma unroll
    for (int j = 0; j < 4; j++) accv[i][j] = (f32x4){0.f,0.f,0.f,0.f};
  f32x4 compa = (f32x4){0.f,0.f,0.f,0.f};
  float lsc = 0.f;   // running sum for row l15 over this thread's keys

  // Swapped QK^T: s[cf][j] = S[qrow=wid*16+l15][key=cf*16+lg*4+j]
  auto qk_mfma = [&](int tn, f32x4* s) {
    const __bf16* kb_ = kbuf + (tn & 1) * 4096;
    #pragma unroll
    for (int cf = 0; cf < 4; cf++) s[cf] = (f32x4){0.f,0.f,0.f,0.f};
    #pragma unroll
    for (int cf = 0; cf < 4; cf++) {
      int key = cf*16 + l15, swz = key & 7;
      bfrag ka  = *(const bfrag*)(kb_ + key*64 + ((lg     ^ swz) * 8));
      bfrag kb2 = *(const bfrag*)(kb_ + key*64 + (((lg+4) ^ swz) * 8));
      s[cf] = MFMA(ka, qf0, s[cf]);
      s[cf] = MFMA(kb2, qf1, s[cf]);
    }
  };
  // no-max softmax + packed P-write
  auto qk_finish = [&](int tn, f32x4* s) {
    int row = wid*16 + l15;
    char* base = (char*)Pl + (tn & 1)*16384 + row*128;
    int swz = (row & 7) << 4;
    #pragma unroll
    for (int cf = 0; cf < 4; cf++) {
      float p0 = fexp2(s[cf][0] * 1.44269504f);
      float p1 = fexp2(s[cf][1] * 1.44269504f);
      float p2 = fexp2(s[cf][2] * 1.44269504f);
      float p3 = fexp2(s[cf][3] * 1.44269504f);
      lsc += (p0 + p1) + (p2 + p3);
      uint2 pk;
      pk.x = cvtpk(p0, p1);
      pk.y = cvtpk(p2, p3);
      *(uint2*)(base + ((cf*32 + lg*8) ^ swz)) = pk;   // keys cf*16+lg*4 .. +4
    }
  };

  __syncthreads();   // K tile 0 staged (vmcnt drained)

  // prologue: P(0), then issue DMA K1
  {
    f32x4 s0[4];
    qk_mfma(0, s0);
    qk_finish(0, s0);
  }
  stageK(1);

  for (int t = 0; t < 32; t++) {
    const int k0 = t * 64, pb = t & 1;
    __syncthreads();   // P(t) visible; K(t+1) staged; prior tile's operands consumed
    // issue async K stage for t+2 into kbuf[t&1] (its readers QK(t) finished pre-barrier)
    if (t + 2 < 32) stageK(t + 2);
    // operand loads for tile t
    const __bf16* vwp = VTb + (size_t)(512 + l15)*2048 + k0 + lg*8;
    bfrag vw0 = *(const bfrag*)(vwp);
    bfrag vw1 = *(const bfrag*)(vwp + 32);
    bfrag vb[4][2];
    #pragma unroll
    for (int cf = 0; cf < 4; cf++) {
      const __bf16* vp = VTb + (size_t)(wid*64 + cf*16 + l15)*2048 + k0 + lg*8;
      vb[cf][0] = *(const bfrag*)(vp);
      vb[cf][1] = *(const bfrag*)(vp + 32);
    }
    // QK MFMAs for t+1 (scores stay in regs)
    f32x4 s[4];
    if (t < 31) qk_mfma(t + 1, s);
    // ---- comp(t) += P_own @ vw ----
    {
      int prow = wid*16 + l15;
      int swz = (prow & 7) << 4;
      const char* pbase = (const char*)Pl + pb*16384 + prow*128;
      bfrag pa0 = *(const bfrag*)(pbase + ((lg*16) ^ swz));
      bfrag pa1 = *(const bfrag*)(pbase + ((64 + lg*16) ^ swz));
      compa = MFMA(pa0, vw0, compa);
      compa = MFMA(pa1, vw1, compa);
    }
    // ---- PV(t) first half: rf 0..3 ----
    __builtin_amdgcn_s_setprio(1);
    #pragma unroll
    for (int rf = 0; rf < 4; rf++) {
      int prow = rf*16 + l15;
      int swz = (prow & 7) << 4;
      const char* pbase = (const char*)Pl + pb*16384 + prow*128;
      bfrag pa0 = *(const bfrag*)(pbase + ((lg*16) ^ swz));
      bfrag pa1 = *(const bfrag*)(pbase + ((64 + lg*16) ^ swz));
      #pragma unroll
      for (int cf = 0; cf < 4; cf++) {
        accv[rf][cf] = MFMA(pa0, vb[cf][0], accv[rf][cf]);
        accv[rf][cf] = MFMA(pa1, vb[cf][1], accv[rf][cf]);
      }
    }
    __builtin_amdgcn_s_setprio(0);
    // ---- softmax VALU + P-write for t+1, between the MFMA clusters ----
    if (t < 31) qk_finish(t + 1, s);
    // ---- PV(t) second half: rf 4..7 ----
    __builtin_amdgcn_s_setprio(1);
    #pragma unroll
    for (int rf = 4; rf < 8; rf++) {
      int prow = rf*16 + l15;
      int swz = (prow & 7) << 4;
      const char* pbase = (const char*)Pl + pb*16384 + prow*128;
      bfrag pa0 = *(const bfrag*)(pbase + ((lg*16) ^ swz));
      bfrag pa1 = *(const bfrag*)(pbase + ((64 + lg*16) ^ swz));
      #pragma unroll
      for (int cf = 0; cf < 4; cf++) {
        accv[rf][cf] = MFMA(pa0, vb[cf][0], accv[rf][cf]);
        accv[rf][cf] = MFMA(pa1, vb[cf][1], accv[rf][cf]);
      }
    }
    __builtin_amdgcn_s_setprio(0);
  }
  // ---- epilogue ----
  // lf for row l15: sum lsc over the 4 lanes sharing l15 (xor 16, 32)
  float lfall = lsc;
  lfall += __shfl_xor(lfall, 16);
  lfall += __shfl_xor(lfall, 32);
  float lf[4];
  #pragma unroll
  for (int j = 0; j < 4; j++) lf[j] = __shfl(lfall, lg*4 + j);   // row wid*16+lg*4+j
  {
    int rowg = b*2048 + q0 + wid*16 + lg*4;
    float cmp[4];
    #pragma unroll
    for (int j = 0; j < 4; j++) {
      float qdv = qdot[(size_t)(rowg + j)*12 + h];
      cmp[j] = (l15 < 8) ? (compa[j] / lf[j] + qdv) : -INFINITY;
      if (l15 < 8) prevout[((size_t)(rowg + j)*12 + h)*8 + l15] = cmp[j];
    }
    #pragma unroll
    for (int j = 0; j < 4; j++) {
      float rm = cmp[j];
      rm = fmaxf(rm, __shfl_xor(rm, 1));
      rm = fmaxf(rm, __shfl_xor(rm, 2));
      rm = fmaxf(rm, __shfl_xor(rm, 4));
      float e = exp2f((cmp[j] - rm) * 1.44269504f);
      float rs = e;
      rs += __shfl_xor(rs, 1); rs += __shfl_xor(rs, 2); rs += __shfl_xor(rs, 4);
      float wp = e / (rs * lf[j]);
      if (l15 < 8) wlb[(wid*16 + lg*4 + j)*8 + l15] = wp;
    }
  }
  __syncthreads();
  // chunked r-reduction: 4 STATIC chunks of 32 rows; rbuf [8][32][64]bf16 overlaps Pl
  #pragma unroll
  for (int c = 0; c < 4; c++) {
    #pragma unroll
    for (int rr = 0; rr < 2; rr++) {
      int rf = c*2 + rr;   // compile-time: accv stays in registers
      #pragma unroll
      for (int j = 0; j < 4; j++) {
        int row = rf*16 + lg*4 + j;
        int lrow = row - c*32;
        float wp = wlb[row*8 + wid];
        #pragma unroll
        for (int cf = 0; cf < 4; cf++)
          rbuf[((size_t)wid*32 + lrow)*64 + cf*16 + l15] = (__bf16)(accv[rf][cf][j] * wp);
      }
    }
    __syncthreads();
    {
      int row32 = tid >> 4, dc = (tid & 15) * 4;
      float os[4] = {0,0,0,0};
      #pragma unroll
      for (int r = 0; r < 8; r++) {
        bf16x4 v = *(const bf16x4*)&rbuf[((size_t)r*32 + row32)*64 + dc];
        #pragma unroll
        for (int i = 0; i < 4; i++) os[i] += (float)v[i];
      }
      int grow = c*32 + row32;
      bf16x4 ov;
      #pragma unroll
      for (int i = 0; i < 4; i++) ov[i] = (__bf16)os[i];
      *(bf16x4*)&attno[(size_t)(b*2048 + q0 + grow)*768 + h*64 + dc] = ov;
    }
    if (c < 3) __syncthreads();
  }
}

// ---------------- launch ----------------
extern "C" void kernel_launch(void* const* d_in, const int* in_sizes, int n_in,
                              void* d_out, int out_size, void* d_ws, size_t ws_size,
                              hipStream_t stream) {
  (void)in_sizes; (void)n_in; (void)out_size; (void)ws_size;
  const float* x   = (const float*)d_in[0];
  const float* Wq  = (const float*)d_in[1];
  const float* bq  = (const float*)d_in[2];
  const float* Wk  = (const float*)d_in[3];
  const float* bk  = (const float*)d_in[4];
  const float* Wv  = (const float*)d_in[5];
  const float* bv  = (const float*)d_in[6];
  const float* Wqv = (const float*)d_in[7];
  const float* bqv = (const float*)d_in[8];
  const float* Ws  = (const float*)d_in[9];
  const float* bs  = (const float*)d_in[10];
  const float* Wf  = (const float*)d_in[11];
  const float* bfp = (const float*)d_in[12];
  const float* W1  = (const float*)d_in[13];
  const float* b1  = (const float*)d_in[14];
  const float* W2  = (const float*)d_in[15];
  const float* b2  = (const float*)d_in[16];
  const float* g1  = (const float*)d_in[17];
  const float* be1 = (const float*)d_in[18];
  const float* g2  = (const float*)d_in[19];
  const float* be2 = (const float*)d_in[20];

  char* ws = (char*)d_ws;
  __bf16* Cbuf  = (__bf16*)(ws + OFF_C);
  __bf16* xn    = (__bf16*)(ws + OFF_XN);
  __bf16* VTb   = (__bf16*)(ws + OFF_VT);
  float*  qdotb = (float*)(ws + OFF_QDOT);
  __bf16* Wcat  = (__bf16*)(ws + OFF_WCAT);
  float*  bcat  = (float*)(ws + OFF_BCAT);
  __bf16* WfT   = (__bf16*)(ws + OFF_WFT);
  __bf16* W1T   = (__bf16*)(ws + OFF_W1T);
  __bf16* W2T   = (__bf16*)(ws + OFF_W2T);
  __bf16* attno = (__bf16*)(ws + OFF_ATTNO);
  __bf16* out1  = (__bf16*)(ws + OFF_OUT1);
  __bf16* onb   = (__bf16*)(ws + OFF_ON);
  __bf16* h1    = (__bf16*)(ws + OFF_H1);
  float*  outp  = (float*)d_out;
  float*  prevp = outp + 6291456;   // 4*2048*768

  k_ln<float><<<2048, 256, 0, stream>>>(x, g1, be1, xn);
  k_packcat<<<(2432*96 + 255)/256, 256, 0, stream>>>(Wq, Wk, Wv, Wqv, bq, bk, bv, bqv, Wcat, bcat);
  k_packT<<<(768*96 + 255)/256, 256, 0, stream>>>(Wf, WfT, 768, 768, 768*96);
  k_packT<<<(1536*96 + 255)/256, 256, 0, stream>>>(W1, W1T, 1536, 768, 1536*96);
  k_packT<<<(768*192 + 255)/256, 256, 0, stream>>>(W2, W2T, 768, 1536, 768*192);

  k_gemm<768, 0><<<dim3(64, 19), 256, 0, stream>>>(xn, Wcat, bcat, nullptr, nullptr, Cbuf, NC);

  k_vt<<<1024, 256, 0, stream>>>(Cbuf, Ws, VTb);
  k_qdot<<<384, 256, 0, stream>>>(Cbuf, Ws, bs, qdotb);

  k_attn<<<768, 512, 0, stream>>>(Cbuf, VTb, qdotb, attno, prevp);

  k_gemm<768, 1><<<dim3(64, 6), 256, 0, stream>>>(attno, WfT, bfp, x, nullptr, out1, 768);
  k_ln<__bf16><<<2048, 256, 0, stream>>>(out1, g2, be2, onb);
  k_gemm<768, 2><<<dim3(64, 12), 256, 0, stream>>>(onb, W1T, b1, nullptr, nullptr, h1, 1536);
  k_gemm<1536, 3><<<dim3(64, 6), 256, 0, stream>>>(h1, W2T, b2, nullptr, out1, outp, 768);
}

// Round 19
// 501.184 us; speedup vs baseline: 1.0746x; 1.0746x over previous
//
#include <hip/hip_runtime.h>
#include <hip/hip_bf16.h>

// ---------------- types ----------------
typedef __bf16 bfrag  __attribute__((ext_vector_type(8)));  // 8 bf16 = 4 VGPR (MFMA A/B frag)
typedef __bf16 bf16x4 __attribute__((ext_vector_type(4)));
typedef float  f32x4  __attribute__((ext_vector_type(4)));

#define MFMA(a,b,c) __builtin_amdgcn_mfma_f32_16x16x32_bf16(a,b,c,0,0,0)

__device__ __forceinline__ void gl_lds16(const void* g, void* l) {
  __builtin_amdgcn_global_load_lds((const __attribute__((address_space(1))) void*)g,
                                   (__attribute__((address_space(3))) void*)l, 16, 0, 0);
}
// raw 2^x (inputs are small/normal here; avoids OCML guard path)
__device__ __forceinline__ float fexp2(float x) {
  float r;
  asm("v_exp_f32 %0, %1" : "=v"(r) : "v"(x));
  return r;
}
// pack two f32 -> (bf16,bf16) in one u32
__device__ __forceinline__ unsigned cvtpk(float lo, float hi) {
  unsigned r;
  asm("v_cvt_pk_bf16_f32 %0, %1, %2" : "=v"(r) : "v"(lo), "v"(hi));
  return r;
}

// ---------------- problem dims ----------------
// B=4 S=2048 DIM=768 H=12 HD=64 QK=32 R=8
// C (proj out) cols: q[0,768) k[768,1536) v[1536,2048) qv[2048,2432)
#define NC 2432

// ---------------- workspace layout (bytes) ----------------
#define OFF_C     ((size_t)0)           // bf16 [8192][2432]    39,845,888
#define OFF_VT    ((size_t)52428800)    // bf16 [4][512][2048]   8,388,608
#define OFF_QDOT  ((size_t)61079552)    // f32  [4][2048][12]      393,216
#define OFF_WCAT  ((size_t)61472768)    // bf16 [2432][768]      3,735,552
#define OFF_BCAT  ((size_t)65208320)    // f32  [2432]               9,728
#define OFF_WFT   ((size_t)65218048)    // bf16 [768][768]       1,179,648
#define OFF_W1T   ((size_t)66397696)    // bf16 [1536][768]      2,359,296
#define OFF_W2T   ((size_t)68756992)    // bf16 [768][1536]      2,359,296
#define OFF_ATTNO ((size_t)71116288)    // bf16 [8192][768]     12,582,912
#define OFF_XN    ((size_t)39845888)    // bf16 [8192][768]     12,582,912
// reuse (after attention, C/XN/VT dead):
#define OFF_OUT1  ((size_t)0)           // bf16 [8192][768]
#define OFF_ON    ((size_t)12582912)    // bf16 [8192][768]
#define OFF_H1    ((size_t)25165824)    // bf16 [8192][1536]

// ---------------- LayerNorm: wave per row (768 cols) ----------------
template<typename TIN>
__global__ __launch_bounds__(256) void k_ln(const TIN* __restrict__ in,
    const float* __restrict__ g, const float* __restrict__ be, __bf16* __restrict__ out) {
  int row  = blockIdx.x * 4 + (threadIdx.x >> 6);
  int lane = threadIdx.x & 63;
  const TIN* rp = in + (size_t)row * 768;
  float v[12];
  #pragma unroll
  for (int i = 0; i < 3; i++) {
    int c = i * 256 + lane * 4;
    if constexpr (sizeof(TIN) == 4) {
      float4 lv = *(const float4*)(rp + c);
      v[i*4+0] = lv.x; v[i*4+1] = lv.y; v[i*4+2] = lv.z; v[i*4+3] = lv.w;
    } else {
      bf16x4 lv = *(const bf16x4*)(rp + c);
      #pragma unroll
      for (int jj = 0; jj < 4; jj++) v[i*4+jj] = (float)lv[jj];
    }
  }
  float s = 0.f, sq = 0.f;
  #pragma unroll
  for (int k = 0; k < 12; k++) { s += v[k]; sq += v[k]*v[k]; }
  #pragma unroll
  for (int d = 1; d < 64; d <<= 1) { s += __shfl_xor(s, d); sq += __shfl_xor(sq, d); }
  float mean = s * (1.f/768.f);
  float rstd = rsqrtf(sq * (1.f/768.f) - mean*mean + 1e-5f);
  #pragma unroll
  for (int i = 0; i < 3; i++) {
    int c = i * 256 + lane * 4;
    float4 gv = *(const float4*)(g + c);
    float4 bv = *(const float4*)(be + c);
    bf16x4 o;
    o[0] = (__bf16)((v[i*4+0]-mean)*rstd*gv.x + bv.x);
    o[1] = (__bf16)((v[i*4+1]-mean)*rstd*gv.y + bv.y);
    o[2] = (__bf16)((v[i*4+2]-mean)*rstd*gv.z + bv.z);
    o[3] = (__bf16)((v[i*4+3]-mean)*rstd*gv.w + bv.w);
    *(bf16x4*)(out + (size_t)row*768 + c) = o;
  }
}

// ---------------- pack W (transpose f32->bf16, K-major) ----------------
__global__ __launch_bounds__(256) void k_packT(const float* __restrict__ src, __bf16* __restrict__ dst,
                                               int N, int K, int total) {
  int idx = blockIdx.x * 256 + threadIdx.x;
  if (idx >= total) return;
  int K8 = K >> 3;
  int n = idx / K8, k0 = (idx % K8) * 8;
  bfrag o;
  #pragma unroll
  for (int i = 0; i < 8; i++) o[i] = (__bf16)src[(size_t)(k0+i)*N + n];
  *(bfrag*)&dst[(size_t)n*K + k0] = o;
}

__global__ __launch_bounds__(256) void k_packcat(
    const float* __restrict__ Wq, const float* __restrict__ Wk,
    const float* __restrict__ Wv, const float* __restrict__ Wqv,
    const float* __restrict__ bq, const float* __restrict__ bk,
    const float* __restrict__ bv, const float* __restrict__ bqv,
    __bf16* __restrict__ Wt, float* __restrict__ bcat) {
  int idx = blockIdx.x * 256 + threadIdx.x;
  if (idx >= 2432 * 96) return;
  int n = idx / 96, k0 = (idx % 96) * 8;
  const float* src; int col, sN; float sc = 1.f;
  if (n < 768)       { src = Wq;  col = n;        sN = 768; sc = 0.125f; }            // 1/sqrt(64)
  else if (n < 1536) { src = Wk;  col = n - 768;  sN = 768; }
  else if (n < 2048) { src = Wv;  col = n - 1536; sN = 512; }
  else               { src = Wqv; col = n - 2048; sN = 384; sc = 0.1767766952966369f; } // 1/sqrt(32)
  bfrag o;
  #pragma unroll
  for (int i = 0; i < 8; i++) o[i] = (__bf16)(src[(size_t)(k0+i)*sN + col] * sc);
  *(bfrag*)&Wt[(size_t)n*768 + k0] = o;
  if (k0 == 0) {
    float bb;
    if (n < 768) bb = bq[col]*0.125f;
    else if (n < 1536) bb = bk[col];
    else if (n < 2048) bb = bv[col];
    else bb = bqv[col]*0.1767766952966369f;
    bcat[n] = bb;
  }
}

// ---------------- GEMM: [8192,KD]bf16 @ Bt[N,KD]bf16 -> epilogues ----------------
template<int KD, int EPI>
__global__ __launch_bounds__(256, 3) void k_gemm(const __bf16* __restrict__ A,
    const __bf16* __restrict__ Bt, const float* __restrict__ bias,
    const float* __restrict__ resf, const __bf16* __restrict__ resb,
    void* __restrict__ Cout, int N) {
  __shared__ __bf16 Al[2][128*32];
  __shared__ __bf16 Bl[2][128*32];
  // bijective XCD swizzle on m-tiles (gridDim.x == 64 == 8*8)
  const int bx = (blockIdx.x & 7) * 8 + (blockIdx.x >> 3);
  const int m0 = bx * 128, n0 = blockIdx.y * 128;
  const int tid = threadIdx.x, lane = tid & 63, w = tid >> 6;
  const int wm = (w >> 1) * 64, wn = (w & 1) * 64;
  const int srow = lane >> 2, skoff = (lane & 3) * 8;
  const int l15 = lane & 15, lg = lane >> 4;
  f32x4 acc[4][4];
  #pragma unroll
  for (int i = 0; i < 4; i++)
    #pragma unroll
    for (int j = 0; j < 4; j++) acc[i][j] = (f32x4){0.f,0.f,0.f,0.f};
  const int NT = KD / 32;
  auto stage = [&](int buf, int k0) {
    #pragma unroll
    for (int i = 0; i < 2; i++) {
      int c = w * 2 + i;
      gl_lds16(A  + (size_t)(m0 + c*16 + srow) * KD + k0 + skoff, &Al[buf][c*512]);
      gl_lds16(Bt + (size_t)(n0 + c*16 + srow) * KD + k0 + skoff, &Bl[buf][c*512]);
    }
  };
  stage(0, 0);
  __syncthreads();
  for (int t = 0; t < NT; t++) {
    int buf = t & 1;
    if (t + 1 < NT) stage(buf ^ 1, (t + 1) * 32);
    bfrag af[4], bfm[4];
    #pragma unroll
    for (int f = 0; f < 4; f++) {
      af[f]  = *(const bfrag*)&Al[buf][(wm + f*16 + l15)*32 + lg*8];
      bfm[f] = *(const bfrag*)&Bl[buf][(wn + f*16 + l15)*32 + lg*8];
    }
    #pragma unroll
    for (int i = 0; i < 4; i++)
      #pragma unroll
      for (int j = 0; j < 4; j++)
        acc[i][j] = MFMA(af[i], bfm[j], acc[i][j]);
    __syncthreads();
  }
  #pragma unroll
  for (int i = 0; i < 4; i++) {
    int row0 = m0 + wm + i*16 + lg*4;
    #pragma unroll
    for (int j = 0; j < 4; j++) {
      int col = n0 + wn + j*16 + l15;
      float bv = bias[col];
      #pragma unroll
      for (int q = 0; q < 4; q++) {
        size_t r = (size_t)(row0 + q);
        float v = acc[i][j][q] + bv;
        if (EPI == 0)      ((__bf16*)Cout)[r*N + col] = (__bf16)v;
        else if (EPI == 1) { v += resf[r*N + col]; ((__bf16*)Cout)[r*N + col] = (__bf16)v; }
        else if (EPI == 2) ((__bf16*)Cout)[r*N + col] = (__bf16)fmaxf(v, 0.f);
        else               { v += (float)resb[r*N + col]; ((float*)Cout)[r*N + col] = v; }
      }
    }
  }
}

// ---------------- V transpose: VT[b][d][k] = C[b*2048+k][1536+d] ----------------
__global__ __launch_bounds__(256) void k_vt(const __bf16* __restrict__ C, __bf16* __restrict__ VT) {
  int bid = blockIdx.x;
  int b = bid >> 8, dt = (bid >> 5) & 7, kt = bid & 31;
  __shared__ __bf16 tile[64][72];
  int tid = threadIdx.x;
  int r = tid >> 3, c0 = (tid & 7) * 8;
  #pragma unroll
  for (int p = 0; p < 2; p++) {
    int rr = r + p * 32;
    bfrag v = *(const bfrag*)&C[(size_t)(b*2048 + kt*64 + rr)*NC + 1536 + dt*64 + c0];
    *(bfrag*)&tile[rr][c0] = v;
  }
  __syncthreads();
  #pragma unroll
  for (int p = 0; p < 2; p++) {
    int d = r + p * 32;
    bfrag o;
    #pragma unroll
    for (int i = 0; i < 8; i++) o[i] = tile[c0 + i][d];
    *(bfrag*)&VT[((size_t)b*512 + dt*64 + d)*2048 + kt*64 + c0] = o;
  }
}

// ---------------- qdot: qv . ws_q + bs ----------------
__global__ __launch_bounds__(256) void k_qdot(const __bf16* __restrict__ C, const float* __restrict__ Ws,
                                              const float* __restrict__ bs, float* __restrict__ qd) {
  int idx = blockIdx.x * 256 + threadIdx.x;
  if (idx >= 98304) return;
  int h = idx % 12; size_t srow = (size_t)(idx / 12);
  const __bf16* qp = &C[srow*NC + 2048 + h*32];
  float s = bs[0];
  #pragma unroll
  for (int j = 0; j < 32; j++) s += (float)qp[j] * Ws[j];
  qd[idx] = s;
}

// ---------------- fused flash attention + compositional mixing ----------------
// R19: R17 base; per-tile comp MFMA DELETED. comp[row][r] = sum_d out*ws_o[d]
// is computed in the epilogue directly from the final accumulator (accv IS the
// unnormalized out for r=wid, d=cf*16+l15) — the per-tile P@vw (2 MFMA + vw
// loads + P reads, on the critical path) was algebraically redundant.
// LDS map (loop):
//   [0,32768)      Pl dbuf [2][128][128B swizzled]
//   [32768,49152)  kbuf dbuf [2][8192B]
//   [49152,53248)  wlb [128][8] f32  (comp, then rule weights)
// Epilogue: rbuf [8][32][64]bf16 (32KB) overlaps Pl; 4 static chunks of 32 rows.
__global__ __launch_bounds__(512, 2) void k_attn(const __bf16* __restrict__ C,
    const __bf16* __restrict__ VT, const float* __restrict__ Ws,
    const float* __restrict__ qdot, __bf16* __restrict__ attno, float* __restrict__ prevout) {
  __shared__ __align__(16) char smem[53248];
  __bf16* Pl   = (__bf16*)(smem);
  __bf16* kbuf = (__bf16*)(smem + 32768);
  float*  wlb  = (float*)(smem + 49152);
  __bf16* rbuf = (__bf16*)(smem);

  const int tid = threadIdx.x, lane = tid & 63, wid = tid >> 6;
  const int l15 = lane & 15, lg = lane >> 4;
  // bijective XCD swizzle: 768 = 8 * 96
  const int bid = (blockIdx.x & 7) * 96 + (blockIdx.x >> 3);
  const int b = bid / 192, rem = bid % 192, h = rem / 16, qb = rem % 16;
  const int q0 = qb * 128;

  const __bf16* VTb = VT + (size_t)b * 512 * 2048;
  // per-lane pre-swizzled K source in C: thread (key=tid>>3, ch=tid&7) loads
  // K[key][(ch^(key&7))*8 ..+8] of tile 0; tile t adds t*64 rows
  const int kkey = tid >> 3, kch = tid & 7;
  const __bf16* Ksrc0 = C + (size_t)(b*2048 + kkey)*NC + 768 + h*64 + ((kch ^ (kkey & 7)) * 8);

  auto stageK = [&](int t) {
    gl_lds16(Ksrc0 + (size_t)t * 64 * NC, kbuf + (t & 1)*4096 + (size_t)wid*512);
  };
  stageK(0);

  const __bf16* Qbase = C + (size_t)(b*2048 + q0 + wid*16 + l15)*NC + h*64 + lg*8;
  bfrag qf0 = *(const bfrag*)(Qbase);
  bfrag qf1 = *(const bfrag*)(Qbase + 32);

  f32x4 accv[8][4];
  #pragma unroll
  for (int i = 0; i < 8; i++)
    #pragma unroll
    for (int j = 0; j < 4; j++) accv[i][j] = (f32x4){0.f,0.f,0.f,0.f};
  float lsc = 0.f;   // running sum for row l15 over this thread's keys

  // Swapped QK^T + no-max softmax + packed P-write for tile tn.
  // s[cf][j] = S[qrow=wid*16+l15][key=cf*16+lg*4+j]
  auto qk_phase = [&](int tn) {
    const __bf16* kb_ = kbuf + (tn & 1) * 4096;
    f32x4 s[4];
    #pragma unroll
    for (int cf = 0; cf < 4; cf++) s[cf] = (f32x4){0.f,0.f,0.f,0.f};
    #pragma unroll
    for (int cf = 0; cf < 4; cf++) {
      int key = cf*16 + l15, swz = key & 7;
      bfrag ka  = *(const bfrag*)(kb_ + key*64 + ((lg     ^ swz) * 8));
      bfrag kb2 = *(const bfrag*)(kb_ + key*64 + (((lg+4) ^ swz) * 8));
      s[cf] = MFMA(ka, qf0, s[cf]);
      s[cf] = MFMA(kb2, qf1, s[cf]);
    }
    int row = wid*16 + l15;
    char* base = (char*)Pl + (tn & 1)*16384 + row*128;
    int swz = (row & 7) << 4;
    #pragma unroll
    for (int cf = 0; cf < 4; cf++) {
      float p0 = fexp2(s[cf][0] * 1.44269504f);
      float p1 = fexp2(s[cf][1] * 1.44269504f);
      float p2 = fexp2(s[cf][2] * 1.44269504f);
      float p3 = fexp2(s[cf][3] * 1.44269504f);
      lsc += (p0 + p1) + (p2 + p3);
      uint2 pk;
      pk.x = cvtpk(p0, p1);
      pk.y = cvtpk(p2, p3);
      *(uint2*)(base + ((cf*32 + lg*8) ^ swz)) = pk;   // keys cf*16+lg*4 .. +4
    }
  };

  __syncthreads();   // K tile 0 staged (vmcnt drained)

  // prologue: P(0), then issue DMA K1
  qk_phase(0);
  stageK(1);

  for (int t = 0; t < 32; t++) {
    const int k0 = t * 64, pb = t & 1;
    __syncthreads();   // P(t) visible; K(t+1) staged; prior tile's operands consumed
    // issue async K stage for t+2 into kbuf[t&1] (its readers QK(t) finished pre-barrier)
    if (t + 2 < 32) stageK(t + 2);
    // early V loads for tile t (latency hides under QK/softmax of t+1)
    bfrag vb[4][2];
    #pragma unroll
    for (int cf = 0; cf < 4; cf++) {
      const __bf16* vp = VTb + (size_t)(wid*64 + cf*16 + l15)*2048 + k0 + lg*8;
      vb[cf][0] = *(const bfrag*)(vp);
      vb[cf][1] = *(const bfrag*)(vp + 32);
    }
    // pipelined QK^T/softmax/P-write for tile t+1
    if (t < 31) qk_phase(t + 1);
    // ---- PV(t): all 128 rows x own 64 cols ----
    __builtin_amdgcn_s_setprio(1);
    #pragma unroll
    for (int rf = 0; rf < 8; rf++) {
      int prow = rf*16 + l15;
      int swz = (prow & 7) << 4;
      const char* pbase = (const char*)Pl + pb*16384 + prow*128;
      bfrag pa0 = *(const bfrag*)(pbase + ((lg*16) ^ swz));
      bfrag pa1 = *(const bfrag*)(pbase + ((64 + lg*16) ^ swz));
      #pragma unroll
      for (int cf = 0; cf < 4; cf++) {
        accv[rf][cf] = MFMA(pa0, vb[cf][0], accv[rf][cf]);
        accv[rf][cf] = MFMA(pa1, vb[cf][1], accv[rf][cf]);
      }
    }
    __builtin_amdgcn_s_setprio(0);
  }
  // ---- epilogue ----
  // lf for row l15: sum lsc over the 4 lanes sharing l15 (xor 16, 32)
  float lfall = lsc;
  lfall += __shfl_xor(lfall, 16);
  lfall += __shfl_xor(lfall, 32);
  float lf[4];
  #pragma unroll
  for (int j = 0; j < 4; j++) lf[j] = __shfl(lfall, lg*4 + j);   // row wid*16+lg*4+j

  // comp[row][r=wid] = sum_d accv[row][d] * ws_o[d], d = cf*16+l15
  {
    float wso = Ws[32 + l15];          // ws_o[cf*16+l15] loaded per cf below
    float wso1 = Ws[32 + 16 + l15];
    float wso2 = Ws[32 + 32 + l15];
    float wso3 = Ws[32 + 48 + l15];
    #pragma unroll
    for (int rf = 0; rf < 8; rf++) {
      #pragma unroll
      for (int j = 0; j < 4; j++) {
        float cj = accv[rf][0][j]*wso + accv[rf][1][j]*wso1
                 + accv[rf][2][j]*wso2 + accv[rf][3][j]*wso3;
        cj += __shfl_xor(cj, 1); cj += __shfl_xor(cj, 2);
        cj += __shfl_xor(cj, 4); cj += __shfl_xor(cj, 8);
        if (l15 == 0) wlb[(rf*16 + lg*4 + j)*8 + wid] = cj;   // unnormalized comp
      }
    }
  }
  __syncthreads();
  // rule softmax per own rows; read comp from LDS, write wp back to same slots
  {
    int rowg = b*2048 + q0 + wid*16 + lg*4;
    float cmp[4];
    #pragma unroll
    for (int j = 0; j < 4; j++) {
      float qdv = qdot[(size_t)(rowg + j)*12 + h];
      float cv = (l15 < 8) ? wlb[(wid*16 + lg*4 + j)*8 + l15] : 0.f;
      cmp[j] = (l15 < 8) ? (cv / lf[j] + qdv) : -INFINITY;
      if (l15 < 8) prevout[((size_t)(rowg + j)*12 + h)*8 + l15] = cmp[j];
    }
    #pragma unroll
    for (int j = 0; j < 4; j++) {
      float rm = cmp[j];
      rm = fmaxf(rm, __shfl_xor(rm, 1));
      rm = fmaxf(rm, __shfl_xor(rm, 2));
      rm = fmaxf(rm, __shfl_xor(rm, 4));
      float e = exp2f((cmp[j] - rm) * 1.44269504f);
      float rs = e;
      rs += __shfl_xor(rs, 1); rs += __shfl_xor(rs, 2); rs += __shfl_xor(rs, 4);
      float wp = e / (rs * lf[j]);
      if (l15 < 8) wlb[(wid*16 + lg*4 + j)*8 + l15] = wp;   // same lane-slot: safe
    }
  }
  __syncthreads();
  // chunked r-reduction: 4 STATIC chunks of 32 rows; rbuf [8][32][64]bf16 overlaps Pl
  #pragma unroll
  for (int c = 0; c < 4; c++) {
    #pragma unroll
    for (int rr = 0; rr < 2; rr++) {
      int rf = c*2 + rr;   // compile-time: accv stays in registers
      #pragma unroll
      for (int j = 0; j < 4; j++) {
        int row = rf*16 + lg*4 + j;
        int lrow = row - c*32;
        float wp = wlb[row*8 + wid];
        #pragma unroll
        for (int cf = 0; cf < 4; cf++)
          rbuf[((size_t)wid*32 + lrow)*64 + cf*16 + l15] = (__bf16)(accv[rf][cf][j] * wp);
      }
    }
    __syncthreads();
    {
      int row32 = tid >> 4, dc = (tid & 15) * 4;
      float os[4] = {0,0,0,0};
      #pragma unroll
      for (int r = 0; r < 8; r++) {
        bf16x4 v = *(const bf16x4*)&rbuf[((size_t)r*32 + row32)*64 + dc];
        #pragma unroll
        for (int i = 0; i < 4; i++) os[i] += (float)v[i];
      }
      int grow = c*32 + row32;
      bf16x4 ov;
      #pragma unroll
      for (int i = 0; i < 4; i++) ov[i] = (__bf16)os[i];
      *(bf16x4*)&attno[(size_t)(b*2048 + q0 + grow)*768 + h*64 + dc] = ov;
    }
    if (c < 3) __syncthreads();
  }
}

// ---------------- launch ----------------
extern "C" void kernel_launch(void* const* d_in, const int* in_sizes, int n_in,
                              void* d_out, int out_size, void* d_ws, size_t ws_size,
                              hipStream_t stream) {
  (void)in_sizes; (void)n_in; (void)out_size; (void)ws_size;
  const float* x   = (const float*)d_in[0];
  const float* Wq  = (const float*)d_in[1];
  const float* bq  = (const float*)d_in[2];
  const float* Wk  = (const float*)d_in[3];
  const float* bk  = (const float*)d_in[4];
  const float* Wv  = (const float*)d_in[5];
  const float* bv  = (const float*)d_in[6];
  const float* Wqv = (const float*)d_in[7];
  const float* bqv = (const float*)d_in[8];
  const float* Ws  = (const float*)d_in[9];
  const float* bs  = (const float*)d_in[10];
  const float* Wf  = (const float*)d_in[11];
  const float* bfp = (const float*)d_in[12];
  const float* W1  = (const float*)d_in[13];
  const float* b1  = (const float*)d_in[14];
  const float* W2  = (const float*)d_in[15];
  const float* b2  = (const float*)d_in[16];
  const float* g1  = (const float*)d_in[17];
  const float* be1 = (const float*)d_in[18];
  const float* g2  = (const float*)d_in[19];
  const float* be2 = (const float*)d_in[20];

  char* ws = (char*)d_ws;
  __bf16* Cbuf  = (__bf16*)(ws + OFF_C);
  __bf16* xn    = (__bf16*)(ws + OFF_XN);
  __bf16* VTb   = (__bf16*)(ws + OFF_VT);
  float*  qdotb = (float*)(ws + OFF_QDOT);
  __bf16* Wcat  = (__bf16*)(ws + OFF_WCAT);
  float*  bcat  = (float*)(ws + OFF_BCAT);
  __bf16* WfT   = (__bf16*)(ws + OFF_WFT);
  __bf16* W1T   = (__bf16*)(ws + OFF_W1T);
  __bf16* W2T   = (__bf16*)(ws + OFF_W2T);
  __bf16* attno = (__bf16*)(ws + OFF_ATTNO);
  __bf16* out1  = (__bf16*)(ws + OFF_OUT1);
  __bf16* onb   = (__bf16*)(ws + OFF_ON);
  __bf16* h1    = (__bf16*)(ws + OFF_H1);
  float*  outp  = (float*)d_out;
  float*  prevp = outp + 6291456;   // 4*2048*768

  k_ln<float><<<2048, 256, 0, stream>>>(x, g1, be1, xn);
  k_packcat<<<(2432*96 + 255)/256, 256, 0, stream>>>(Wq, Wk, Wv, Wqv, bq, bk, bv, bqv, Wcat, bcat);
  k_packT<<<(768*96 + 255)/256, 256, 0, stream>>>(Wf, WfT, 768, 768, 768*96);
  k_packT<<<(1536*96 + 255)/256, 256, 0, stream>>>(W1, W1T, 1536, 768, 1536*96);
  k_packT<<<(768*192 + 255)/256, 256, 0, stream>>>(W2, W2T, 768, 1536, 768*192);

  k_gemm<768, 0><<<dim3(64, 19), 256, 0, stream>>>(xn, Wcat, bcat, nullptr, nullptr, Cbuf, NC);

  k_vt<<<1024, 256, 0, stream>>>(Cbuf, VTb);
  k_qdot<<<384, 256, 0, stream>>>(Cbuf, Ws, bs, qdotb);

  k_attn<<<768, 512, 0, stream>>>(Cbuf, VTb, Ws, qdotb, attno, prevp);

  k_gemm<768, 1><<<dim3(64, 6), 256, 0, stream>>>(attno, WfT, bfp, x, nullptr, out1, 768);
  k_ln<__bf16><<<2048, 256, 0, stream>>>(out1, g2, be2, onb);
  k_gemm<768, 2><<<dim3(64, 12), 256, 0, stream>>>(onb, W1T, b1, nullptr, nullptr, h1, 1536);
  k_gemm<1536, 3><<<dim3(64, 6), 256, 0, stream>>>(h1, W2T, b2, nullptr, out1, outp, 768);
}

// Round 20
// 480.681 us; speedup vs baseline: 1.1204x; 1.0427x over previous
//
#include <hip/hip_runtime.h>
#include <hip/hip_bf16.h>

// ---------------- types ----------------
typedef __bf16 bfrag  __attribute__((ext_vector_type(8)));  // 8 bf16 = 4 VGPR (MFMA A/B frag)
typedef __bf16 bf16x4 __attribute__((ext_vector_type(4)));
typedef float  f32x4  __attribute__((ext_vector_type(4)));

#define MFMA(a,b,c) __builtin_amdgcn_mfma_f32_16x16x32_bf16(a,b,c,0,0,0)

__device__ __forceinline__ void gl_lds16(const void* g, void* l) {
  __builtin_amdgcn_global_load_lds((const __attribute__((address_space(1))) void*)g,
                                   (__attribute__((address_space(3))) void*)l, 16, 0, 0);
}
// raw 2^x (inputs are small/normal here; avoids OCML guard path)
__device__ __forceinline__ float fexp2(float x) {
  float r;
  asm("v_exp_f32 %0, %1" : "=v"(r) : "v"(x));
  return r;
}
// pack two f32 -> (bf16,bf16) in one u32
__device__ __forceinline__ unsigned cvtpk(float lo, float hi) {
  unsigned r;
  asm("v_cvt_pk_bf16_f32 %0, %1, %2" : "=v"(r) : "v"(lo), "v"(hi));
  return r;
}

// ---------------- problem dims ----------------
// B=4 S=2048 DIM=768 H=12 HD=64 QK=32 R=8
// C (proj out) cols: q[0,768) k[768,1536) v[1536,2048) qv[2048,2432)
#define NC 2432

// ---------------- workspace layout (bytes) ----------------
#define OFF_C     ((size_t)0)           // bf16 [8192][2432]    39,845,888
#define OFF_VT    ((size_t)52428800)    // bf16 [4][512][2048]   8,388,608
#define OFF_QDOT  ((size_t)61079552)    // f32  [4][2048][12]      393,216
#define OFF_WCAT  ((size_t)61472768)    // bf16 [2432][768]      3,735,552
#define OFF_BCAT  ((size_t)65208320)    // f32  [2432]               9,728
#define OFF_WFT   ((size_t)65218048)    // bf16 [768][768]       1,179,648
#define OFF_W1T   ((size_t)66397696)    // bf16 [1536][768]      2,359,296
#define OFF_W2T   ((size_t)68756992)    // bf16 [768][1536]      2,359,296
#define OFF_ATTNO ((size_t)71116288)    // bf16 [8192][768]     12,582,912
#define OFF_XN    ((size_t)39845888)    // bf16 [8192][768]     12,582,912
// reuse (after attention, C/XN/VT dead):
#define OFF_OUT1  ((size_t)0)           // bf16 [8192][768]
#define OFF_ON    ((size_t)12582912)    // bf16 [8192][768]
#define OFF_H1    ((size_t)25165824)    // bf16 [8192][1536]

// ---------------- LayerNorm: wave per row (768 cols) ----------------
template<typename TIN>
__global__ __launch_bounds__(256) void k_ln(const TIN* __restrict__ in,
    const float* __restrict__ g, const float* __restrict__ be, __bf16* __restrict__ out) {
  int row  = blockIdx.x * 4 + (threadIdx.x >> 6);
  int lane = threadIdx.x & 63;
  const TIN* rp = in + (size_t)row * 768;
  float v[12];
  #pragma unroll
  for (int i = 0; i < 3; i++) {
    int c = i * 256 + lane * 4;
    if constexpr (sizeof(TIN) == 4) {
      float4 lv = *(const float4*)(rp + c);
      v[i*4+0] = lv.x; v[i*4+1] = lv.y; v[i*4+2] = lv.z; v[i*4+3] = lv.w;
    } else {
      bf16x4 lv = *(const bf16x4*)(rp + c);
      #pragma unroll
      for (int jj = 0; jj < 4; jj++) v[i*4+jj] = (float)lv[jj];
    }
  }
  float s = 0.f, sq = 0.f;
  #pragma unroll
  for (int k = 0; k < 12; k++) { s += v[k]; sq += v[k]*v[k]; }
  #pragma unroll
  for (int d = 1; d < 64; d <<= 1) { s += __shfl_xor(s, d); sq += __shfl_xor(sq, d); }
  float mean = s * (1.f/768.f);
  float rstd = rsqrtf(sq * (1.f/768.f) - mean*mean + 1e-5f);
  #pragma unroll
  for (int i = 0; i < 3; i++) {
    int c = i * 256 + lane * 4;
    float4 gv = *(const float4*)(g + c);
    float4 bv = *(const float4*)(be + c);
    bf16x4 o;
    o[0] = (__bf16)((v[i*4+0]-mean)*rstd*gv.x + bv.x);
    o[1] = (__bf16)((v[i*4+1]-mean)*rstd*gv.y + bv.y);
    o[2] = (__bf16)((v[i*4+2]-mean)*rstd*gv.z + bv.z);
    o[3] = (__bf16)((v[i*4+3]-mean)*rstd*gv.w + bv.w);
    *(bf16x4*)(out + (size_t)row*768 + c) = o;
  }
}

// ---------------- merged weight packing: packcat + 3x packT in one launch ----------------
__device__ __forceinline__ void packT_body(const float* __restrict__ src, __bf16* __restrict__ dst,
                                           int N, int K, int idx) {
  int K8 = K >> 3;
  int n = idx / K8, k0 = (idx % K8) * 8;
  bfrag o;
  #pragma unroll
  for (int i = 0; i < 8; i++) o[i] = (__bf16)src[(size_t)(k0+i)*N + n];
  *(bfrag*)&dst[(size_t)n*K + k0] = o;
}

__global__ __launch_bounds__(256) void k_packall(
    const float* __restrict__ Wq, const float* __restrict__ Wk,
    const float* __restrict__ Wv, const float* __restrict__ Wqv,
    const float* __restrict__ bq, const float* __restrict__ bk,
    const float* __restrict__ bv, const float* __restrict__ bqv,
    const float* __restrict__ Wf, const float* __restrict__ W1, const float* __restrict__ W2,
    __bf16* __restrict__ Wcat, float* __restrict__ bcat,
    __bf16* __restrict__ WfT, __bf16* __restrict__ W1T, __bf16* __restrict__ W2T) {
  int bidx = blockIdx.x;
  if (bidx < 912) {
    // packcat: Wq|Wk|Wv|Wqv -> Wcat [2432][768], bias cat
    int idx = bidx * 256 + threadIdx.x;
    if (idx >= 2432 * 96) return;
    int n = idx / 96, k0 = (idx % 96) * 8;
    const float* src; int col, sN; float sc = 1.f;
    if (n < 768)       { src = Wq;  col = n;        sN = 768; sc = 0.125f; }
    else if (n < 1536) { src = Wk;  col = n - 768;  sN = 768; }
    else if (n < 2048) { src = Wv;  col = n - 1536; sN = 512; }
    else               { src = Wqv; col = n - 2048; sN = 384; sc = 0.1767766952966369f; }
    bfrag o;
    #pragma unroll
    for (int i = 0; i < 8; i++) o[i] = (__bf16)(src[(size_t)(k0+i)*sN + col] * sc);
    *(bfrag*)&Wcat[(size_t)n*768 + k0] = o;
    if (k0 == 0) {
      float bb;
      if (n < 768) bb = bq[col]*0.125f;
      else if (n < 1536) bb = bk[col];
      else if (n < 2048) bb = bv[col];
      else bb = bqv[col]*0.1767766952966369f;
      bcat[n] = bb;
    }
  } else if (bidx < 1200) {
    int idx = (bidx - 912) * 256 + threadIdx.x;
    if (idx < 768*96) packT_body(Wf, WfT, 768, 768, idx);
  } else if (bidx < 1776) {
    int idx = (bidx - 1200) * 256 + threadIdx.x;
    if (idx < 1536*96) packT_body(W1, W1T, 1536, 768, idx);
  } else {
    int idx = (bidx - 1776) * 256 + threadIdx.x;
    if (idx < 768*192) packT_body(W2, W2T, 768, 1536, idx);
  }
}

// ---------------- GEMM: [8192,KD]bf16 @ Bt[N,KD]bf16 -> epilogues ----------------
template<int KD, int EPI>
__global__ __launch_bounds__(256, 3) void k_gemm(const __bf16* __restrict__ A,
    const __bf16* __restrict__ Bt, const float* __restrict__ bias,
    const float* __restrict__ resf, const __bf16* __restrict__ resb,
    void* __restrict__ Cout, int N) {
  __shared__ __bf16 Al[2][128*32];
  __shared__ __bf16 Bl[2][128*32];
  // bijective XCD swizzle on m-tiles (gridDim.x == 64 == 8*8)
  const int bx = (blockIdx.x & 7) * 8 + (blockIdx.x >> 3);
  const int m0 = bx * 128, n0 = blockIdx.y * 128;
  const int tid = threadIdx.x, lane = tid & 63, w = tid >> 6;
  const int wm = (w >> 1) * 64, wn = (w & 1) * 64;
  const int srow = lane >> 2, skoff = (lane & 3) * 8;
  const int l15 = lane & 15, lg = lane >> 4;
  f32x4 acc[4][4];
  #pragma unroll
  for (int i = 0; i < 4; i++)
    #pragma unroll
    for (int j = 0; j < 4; j++) acc[i][j] = (f32x4){0.f,0.f,0.f,0.f};
  const int NT = KD / 32;
  auto stage = [&](int buf, int k0) {
    #pragma unroll
    for (int i = 0; i < 2; i++) {
      int c = w * 2 + i;
      gl_lds16(A  + (size_t)(m0 + c*16 + srow) * KD + k0 + skoff, &Al[buf][c*512]);
      gl_lds16(Bt + (size_t)(n0 + c*16 + srow) * KD + k0 + skoff, &Bl[buf][c*512]);
    }
  };
  stage(0, 0);
  __syncthreads();
  for (int t = 0; t < NT; t++) {
    int buf = t & 1;
    if (t + 1 < NT) stage(buf ^ 1, (t + 1) * 32);
    bfrag af[4], bfm[4];
    #pragma unroll
    for (int f = 0; f < 4; f++) {
      af[f]  = *(const bfrag*)&Al[buf][(wm + f*16 + l15)*32 + lg*8];
      bfm[f] = *(const bfrag*)&Bl[buf][(wn + f*16 + l15)*32 + lg*8];
    }
    #pragma unroll
    for (int i = 0; i < 4; i++)
      #pragma unroll
      for (int j = 0; j < 4; j++)
        acc[i][j] = MFMA(af[i], bfm[j], acc[i][j]);
    __syncthreads();
  }
  #pragma unroll
  for (int i = 0; i < 4; i++) {
    int row0 = m0 + wm + i*16 + lg*4;
    #pragma unroll
    for (int j = 0; j < 4; j++) {
      int col = n0 + wn + j*16 + l15;
      float bv = bias[col];
      #pragma unroll
      for (int q = 0; q < 4; q++) {
        size_t r = (size_t)(row0 + q);
        float v = acc[i][j][q] + bv;
        if (EPI == 0)      ((__bf16*)Cout)[r*N + col] = (__bf16)v;
        else if (EPI == 1) { v += resf[r*N + col]; ((__bf16*)Cout)[r*N + col] = (__bf16)v; }
        else if (EPI == 2) ((__bf16*)Cout)[r*N + col] = (__bf16)fmaxf(v, 0.f);
        else               { v += (float)resb[r*N + col]; ((float*)Cout)[r*N + col] = v; }
      }
    }
  }
}

// ---------------- V transpose + fused qdot ----------------
// VT[b][d][k] = C[b*2048+k][1536+d]; dt==0 blocks additionally compute
// qdot[row][h] = qv[row][h*32..+32] . ws_q + bs for their 64 rows.
__global__ __launch_bounds__(256) void k_vt(const __bf16* __restrict__ C, const float* __restrict__ Ws,
                                            const float* __restrict__ bs,
                                            __bf16* __restrict__ VT, float* __restrict__ qd) {
  int bid = blockIdx.x;
  int b = bid >> 8, dt = (bid >> 5) & 7, kt = bid & 31;
  __shared__ __bf16 tile[64][72];
  int tid = threadIdx.x;
  int r = tid >> 3, c0 = (tid & 7) * 8;
  #pragma unroll
  for (int p = 0; p < 2; p++) {
    int rr = r + p * 32;
    bfrag v = *(const bfrag*)&C[(size_t)(b*2048 + kt*64 + rr)*NC + 1536 + dt*64 + c0];
    *(bfrag*)&tile[rr][c0] = v;
  }
  __syncthreads();
  #pragma unroll
  for (int p = 0; p < 2; p++) {
    int d = r + p * 32;
    bfrag o;
    #pragma unroll
    for (int i = 0; i < 8; i++) o[i] = tile[c0 + i][d];
    *(bfrag*)&VT[((size_t)b*512 + dt*64 + d)*2048 + kt*64 + c0] = o;
  }
  // fused qdot: dt==0 blocks cover rows kt*64..+64 (64 rows x 12 h = 768 dots)
  if (dt == 0) {
    float bsv = bs[0];
    #pragma unroll
    for (int p = 0; p < 3; p++) {
      int idx = p * 256 + tid;   // < 768
      int rl = idx / 12, h = idx % 12;
      size_t srow = (size_t)(b*2048 + kt*64 + rl);
      const __bf16* qp = &C[srow*NC + 2048 + h*32];
      float s = bsv;
      #pragma unroll
      for (int c = 0; c < 4; c++) {
        bfrag v = *(const bfrag*)(qp + c*8);
        #pragma unroll
        for (int i = 0; i < 8; i++) s += (float)v[i] * Ws[c*8 + i];
      }
      qd[srow*12 + h] = s;
    }
  }
}

// ---------------- fused flash attention + compositional mixing ----------------
// R20: R19 minus s_setprio (lockstep waves: m190 config where setprio hurt).
// Per-tile comp deleted (R19); no-max softmax; swapped QK^T; packed P-writes;
// direct-from-C K staging with pre-swizzled per-lane source; XCD swizzle.
// LDS map (loop):
//   [0,32768)      Pl dbuf [2][128][128B swizzled]
//   [32768,49152)  kbuf dbuf [2][8192B]
//   [49152,53248)  wlb [128][8] f32  (comp, then rule weights)
// Epilogue: rbuf [8][32][64]bf16 (32KB) overlaps Pl; 4 static chunks of 32 rows.
__global__ __launch_bounds__(512, 2) void k_attn(const __bf16* __restrict__ C,
    const __bf16* __restrict__ VT, const float* __restrict__ Ws,
    const float* __restrict__ qdot, __bf16* __restrict__ attno, float* __restrict__ prevout) {
  __shared__ __align__(16) char smem[53248];
  __bf16* Pl   = (__bf16*)(smem);
  __bf16* kbuf = (__bf16*)(smem + 32768);
  float*  wlb  = (float*)(smem + 49152);
  __bf16* rbuf = (__bf16*)(smem);

  const int tid = threadIdx.x, lane = tid & 63, wid = tid >> 6;
  const int l15 = lane & 15, lg = lane >> 4;
  // bijective XCD swizzle: 768 = 8 * 96
  const int bid = (blockIdx.x & 7) * 96 + (blockIdx.x >> 3);
  const int b = bid / 192, rem = bid % 192, h = rem / 16, qb = rem % 16;
  const int q0 = qb * 128;

  const __bf16* VTb = VT + (size_t)b * 512 * 2048;
  // per-lane pre-swizzled K source in C: thread (key=tid>>3, ch=tid&7) loads
  // K[key][(ch^(key&7))*8 ..+8] of tile 0; tile t adds t*64 rows
  const int kkey = tid >> 3, kch = tid & 7;
  const __bf16* Ksrc0 = C + (size_t)(b*2048 + kkey)*NC + 768 + h*64 + ((kch ^ (kkey & 7)) * 8);

  auto stageK = [&](int t) {
    gl_lds16(Ksrc0 + (size_t)t * 64 * NC, kbuf + (t & 1)*4096 + (size_t)wid*512);
  };
  stageK(0);

  const __bf16* Qbase = C + (size_t)(b*2048 + q0 + wid*16 + l15)*NC + h*64 + lg*8;
  bfrag qf0 = *(const bfrag*)(Qbase);
  bfrag qf1 = *(const bfrag*)(Qbase + 32);

  f32x4 accv[8][4];
  #pragma unroll
  for (int i = 0; i < 8; i++)
    #pragma unroll
    for (int j = 0; j < 4; j++) accv[i][j] = (f32x4){0.f,0.f,0.f,0.f};
  float lsc = 0.f;   // running sum for row l15 over this thread's keys

  // Swapped QK^T + no-max softmax + packed P-write for tile tn.
  // s[cf][j] = S[qrow=wid*16+l15][key=cf*16+lg*4+j]
  auto qk_phase = [&](int tn) {
    const __bf16* kb_ = kbuf + (tn & 1) * 4096;
    f32x4 s[4];
    #pragma unroll
    for (int cf = 0; cf < 4; cf++) s[cf] = (f32x4){0.f,0.f,0.f,0.f};
    #pragma unroll
    for (int cf = 0; cf < 4; cf++) {
      int key = cf*16 + l15, swz = key & 7;
      bfrag ka  = *(const bfrag*)(kb_ + key*64 + ((lg     ^ swz) * 8));
      bfrag kb2 = *(const bfrag*)(kb_ + key*64 + (((lg+4) ^ swz) * 8));
      s[cf] = MFMA(ka, qf0, s[cf]);
      s[cf] = MFMA(kb2, qf1, s[cf]);
    }
    int row = wid*16 + l15;
    char* base = (char*)Pl + (tn & 1)*16384 + row*128;
    int swz = (row & 7) << 4;
    #pragma unroll
    for (int cf = 0; cf < 4; cf++) {
      float p0 = fexp2(s[cf][0] * 1.44269504f);
      float p1 = fexp2(s[cf][1] * 1.44269504f);
      float p2 = fexp2(s[cf][2] * 1.44269504f);
      float p3 = fexp2(s[cf][3] * 1.44269504f);
      lsc += (p0 + p1) + (p2 + p3);
      uint2 pk;
      pk.x = cvtpk(p0, p1);
      pk.y = cvtpk(p2, p3);
      *(uint2*)(base + ((cf*32 + lg*8) ^ swz)) = pk;   // keys cf*16+lg*4 .. +4
    }
  };

  __syncthreads();   // K tile 0 staged (vmcnt drained)

  // prologue: P(0), then issue DMA K1
  qk_phase(0);
  stageK(1);

  for (int t = 0; t < 32; t++) {
    const int k0 = t * 64, pb = t & 1;
    __syncthreads();   // P(t) visible; K(t+1) staged; prior tile's operands consumed
    // issue async K stage for t+2 into kbuf[t&1] (its readers QK(t) finished pre-barrier)
    if (t + 2 < 32) stageK(t + 2);
    // early V loads for tile t (latency hides under QK/softmax of t+1)
    bfrag vb[4][2];
    #pragma unroll
    for (int cf = 0; cf < 4; cf++) {
      const __bf16* vp = VTb + (size_t)(wid*64 + cf*16 + l15)*2048 + k0 + lg*8;
      vb[cf][0] = *(const bfrag*)(vp);
      vb[cf][1] = *(const bfrag*)(vp + 32);
    }
    // pipelined QK^T/softmax/P-write for tile t+1
    if (t < 31) qk_phase(t + 1);
    // ---- PV(t): all 128 rows x own 64 cols ----
    #pragma unroll
    for (int rf = 0; rf < 8; rf++) {
      int prow = rf*16 + l15;
      int swz = (prow & 7) << 4;
      const char* pbase = (const char*)Pl + pb*16384 + prow*128;
      bfrag pa0 = *(const bfrag*)(pbase + ((lg*16) ^ swz));
      bfrag pa1 = *(const bfrag*)(pbase + ((64 + lg*16) ^ swz));
      #pragma unroll
      for (int cf = 0; cf < 4; cf++) {
        accv[rf][cf] = MFMA(pa0, vb[cf][0], accv[rf][cf]);
        accv[rf][cf] = MFMA(pa1, vb[cf][1], accv[rf][cf]);
      }
    }
  }
  // ---- epilogue ----
  // lf for row l15: sum lsc over the 4 lanes sharing l15 (xor 16, 32)
  float lfall = lsc;
  lfall += __shfl_xor(lfall, 16);
  lfall += __shfl_xor(lfall, 32);
  float lf[4];
  #pragma unroll
  for (int j = 0; j < 4; j++) lf[j] = __shfl(lfall, lg*4 + j);   // row wid*16+lg*4+j

  // comp[row][r=wid] = sum_d accv[row][d] * ws_o[d], d = cf*16+l15
  {
    float wso = Ws[32 + l15];
    float wso1 = Ws[32 + 16 + l15];
    float wso2 = Ws[32 + 32 + l15];
    float wso3 = Ws[32 + 48 + l15];
    #pragma unroll
    for (int rf = 0; rf < 8; rf++) {
      #pragma unroll
      for (int j = 0; j < 4; j++) {
        float cj = accv[rf][0][j]*wso + accv[rf][1][j]*wso1
                 + accv[rf][2][j]*wso2 + accv[rf][3][j]*wso3;
        cj += __shfl_xor(cj, 1); cj += __shfl_xor(cj, 2);
        cj += __shfl_xor(cj, 4); cj += __shfl_xor(cj, 8);
        if (l15 == 0) wlb[(rf*16 + lg*4 + j)*8 + wid] = cj;   // unnormalized comp
      }
    }
  }
  __syncthreads();
  // rule softmax per own rows; read comp from LDS, write wp back to same slots
  {
    int rowg = b*2048 + q0 + wid*16 + lg*4;
    float cmp[4];
    #pragma unroll
    for (int j = 0; j < 4; j++) {
      float qdv = qdot[(size_t)(rowg + j)*12 + h];
      float cv = (l15 < 8) ? wlb[(wid*16 + lg*4 + j)*8 + l15] : 0.f;
      cmp[j] = (l15 < 8) ? (cv / lf[j] + qdv) : -INFINITY;
      if (l15 < 8) prevout[((size_t)(rowg + j)*12 + h)*8 + l15] = cmp[j];
    }
    #pragma unroll
    for (int j = 0; j < 4; j++) {
      float rm = cmp[j];
      rm = fmaxf(rm, __shfl_xor(rm, 1));
      rm = fmaxf(rm, __shfl_xor(rm, 2));
      rm = fmaxf(rm, __shfl_xor(rm, 4));
      float e = exp2f((cmp[j] - rm) * 1.44269504f);
      float rs = e;
      rs += __shfl_xor(rs, 1); rs += __shfl_xor(rs, 2); rs += __shfl_xor(rs, 4);
      float wp = e / (rs * lf[j]);
      if (l15 < 8) wlb[(wid*16 + lg*4 + j)*8 + l15] = wp;   // same lane-slot: safe
    }
  }
  __syncthreads();
  // chunked r-reduction: 4 STATIC chunks of 32 rows; rbuf [8][32][64]bf16 overlaps Pl
  #pragma unroll
  for (int c = 0; c < 4; c++) {
    #pragma unroll
    for (int rr = 0; rr < 2; rr++) {
      int rf = c*2 + rr;   // compile-time: accv stays in registers
      #pragma unroll
      for (int j = 0; j < 4; j++) {
        int row = rf*16 + lg*4 + j;
        int lrow = row - c*32;
        float wp = wlb[row*8 + wid];
        #pragma unroll
        for (int cf = 0; cf < 4; cf++)
          rbuf[((size_t)wid*32 + lrow)*64 + cf*16 + l15] = (__bf16)(accv[rf][cf][j] * wp);
      }
    }
    __syncthreads();
    {
      int row32 = tid >> 4, dc = (tid & 15) * 4;
      float os[4] = {0,0,0,0};
      #pragma unroll
      for (int r = 0; r < 8; r++) {
        bf16x4 v = *(const bf16x4*)&rbuf[((size_t)r*32 + row32)*64 + dc];
        #pragma unroll
        for (int i = 0; i < 4; i++) os[i] += (float)v[i];
      }
      int grow = c*32 + row32;
      bf16x4 ov;
      #pragma unroll
      for (int i = 0; i < 4; i++) ov[i] = (__bf16)os[i];
      *(bf16x4*)&attno[(size_t)(b*2048 + q0 + grow)*768 + h*64 + dc] = ov;
    }
    if (c < 3) __syncthreads();
  }
}

// ---------------- launch ----------------
extern "C" void kernel_launch(void* const* d_in, const int* in_sizes, int n_in,
                              void* d_out, int out_size, void* d_ws, size_t ws_size,
                              hipStream_t stream) {
  (void)in_sizes; (void)n_in; (void)out_size; (void)ws_size;
  const float* x   = (const float*)d_in[0];
  const float* Wq  = (const float*)d_in[1];
  const float* bq  = (const float*)d_in[2];
  const float* Wk  = (const float*)d_in[3];
  const float* bk  = (const float*)d_in[4];
  const float* Wv  = (const float*)d_in[5];
  const float* bv  = (const float*)d_in[6];
  const float* Wqv = (const float*)d_in[7];
  const float* bqv = (const float*)d_in[8];
  const float* Ws  = (const float*)d_in[9];
  const float* bs  = (const float*)d_in[10];
  const float* Wf  = (const float*)d_in[11];
  const float* bfp = (const float*)d_in[12];
  const float* W1  = (const float*)d_in[13];
  const float* b1  = (const float*)d_in[14];
  const float* W2  = (const float*)d_in[15];
  const float* b2  = (const float*)d_in[16];
  const float* g1  = (const float*)d_in[17];
  const float* be1 = (const float*)d_in[18];
  const float* g2  = (const float*)d_in[19];
  const float* be2 = (const float*)d_in[20];

  char* ws = (char*)d_ws;
  __bf16* Cbuf  = (__bf16*)(ws + OFF_C);
  __bf16* xn    = (__bf16*)(ws + OFF_XN);
  __bf16* VTb   = (__bf16*)(ws + OFF_VT);
  float*  qdotb = (float*)(ws + OFF_QDOT);
  __bf16* Wcat  = (__bf16*)(ws + OFF_WCAT);
  float*  bcat  = (float*)(ws + OFF_BCAT);
  __bf16* WfT   = (__bf16*)(ws + OFF_WFT);
  __bf16* W1T   = (__bf16*)(ws + OFF_W1T);
  __bf16* W2T   = (__bf16*)(ws + OFF_W2T);
  __bf16* attno = (__bf16*)(ws + OFF_ATTNO);
  __bf16* out1  = (__bf16*)(ws + OFF_OUT1);
  __bf16* onb   = (__bf16*)(ws + OFF_ON);
  __bf16* h1    = (__bf16*)(ws + OFF_H1);
  float*  outp  = (float*)d_out;
  float*  prevp = outp + 6291456;   // 4*2048*768

  k_ln<float><<<2048, 256, 0, stream>>>(x, g1, be1, xn);
  k_packall<<<2352, 256, 0, stream>>>(Wq, Wk, Wv, Wqv, bq, bk, bv, bqv,
                                      Wf, W1, W2, Wcat, bcat, WfT, W1T, W2T);

  k_gemm<768, 0><<<dim3(64, 19), 256, 0, stream>>>(xn, Wcat, bcat, nullptr, nullptr, Cbuf, NC);

  k_vt<<<1024, 256, 0, stream>>>(Cbuf, Ws, bs, VTb, qdotb);

  k_attn<<<768, 512, 0, stream>>>(Cbuf, VTb, Ws, qdotb, attno, prevp);

  k_gemm<768, 1><<<dim3(64, 6), 256, 0, stream>>>(attno, WfT, bfp, x, nullptr, out1, 768);
  k_ln<__bf16><<<2048, 256, 0, stream>>>(out1, g2, be2, onb);
  k_gemm<768, 2><<<dim3(64, 12), 256, 0, stream>>>(onb, W1T, b1, nullptr, nullptr, h1, 1536);
  k_gemm<1536, 3><<<dim3(64, 6), 256, 0, stream>>>(h1, W2T, b2, nullptr, out1, outp, 768);
}

// Round 22
// 472.276 us; speedup vs baseline: 1.1404x; 1.0178x over previous
//
#include <hip/hip_runtime.h>
#include <hip/hip_bf16.h>

// ---------------- types ----------------
typedef __bf16 bfrag  __attribute__((ext_vector_type(8)));  // 8 bf16 = 4 VGPR (MFMA A/B frag)
typedef __bf16 bf16x4 __attribute__((ext_vector_type(4)));
typedef float  f32x4  __attribute__((ext_vector_type(4)));

#define MFMA(a,b,c) __builtin_amdgcn_mfma_f32_16x16x32_bf16(a,b,c,0,0,0)

__device__ __forceinline__ void gl_lds16(const void* g, void* l) {
  __builtin_amdgcn_global_load_lds((const __attribute__((address_space(1))) void*)g,
                                   (__attribute__((address_space(3))) void*)l, 16, 0, 0);
}
// raw 2^x (inputs are small/normal here; avoids OCML guard path)
__device__ __forceinline__ float fexp2(float x) {
  float r;
  asm("v_exp_f32 %0, %1" : "=v"(r) : "v"(x));
  return r;
}
// pack two f32 -> (bf16,bf16) in one u32
__device__ __forceinline__ unsigned cvtpk(float lo, float hi) {
  unsigned r;
  asm("v_cvt_pk_bf16_f32 %0, %1, %2" : "=v"(r) : "v"(lo), "v"(hi));
  return r;
}

// ---------------- problem dims ----------------
// B=4 S=2048 DIM=768 H=12 HD=64 QK=32 R=8
// C (proj out) cols: q[0,768) k[768,1536) v[1536,2048) qv[2048,2432)
#define NC 2432

// ---------------- workspace layout (bytes) ----------------
#define OFF_C     ((size_t)0)           // bf16 [8192][2432]    39,845,888
#define OFF_VT    ((size_t)52428800)    // bf16 [4][512][2048]   8,388,608
#define OFF_QDOT  ((size_t)61079552)    // f32  [4][2048][12]      393,216
#define OFF_WCAT  ((size_t)61472768)    // bf16 [2432][768]      3,735,552
#define OFF_BCAT  ((size_t)65208320)    // f32  [2432]               9,728
#define OFF_WFT   ((size_t)65218048)    // bf16 [768][768]       1,179,648
#define OFF_W1T   ((size_t)66397696)    // bf16 [1536][768]      2,359,296
#define OFF_W2T   ((size_t)68756992)    // bf16 [768][1536]      2,359,296
#define OFF_ATTNO ((size_t)71116288)    // bf16 [8192][768]     12,582,912
#define OFF_XN    ((size_t)39845888)    // bf16 [8192][768]     12,582,912
// reuse (after attention, C/XN/VT dead):
#define OFF_OUT1  ((size_t)0)           // bf16 [8192][768]
#define OFF_ON    ((size_t)12582912)    // bf16 [8192][768]
#define OFF_H1    ((size_t)25165824)    // bf16 [8192][1536]

// ---------------- LayerNorm: wave per row (768 cols) ----------------
template<typename TIN>
__global__ __launch_bounds__(256) void k_ln(const TIN* __restrict__ in,
    const float* __restrict__ g, const float* __restrict__ be, __bf16* __restrict__ out) {
  int row  = blockIdx.x * 4 + (threadIdx.x >> 6);
  int lane = threadIdx.x & 63;
  const TIN* rp = in + (size_t)row * 768;
  float v[12];
  #pragma unroll
  for (int i = 0; i < 3; i++) {
    int c = i * 256 + lane * 4;
    if constexpr (sizeof(TIN) == 4) {
      float4 lv = *(const float4*)(rp + c);
      v[i*4+0] = lv.x; v[i*4+1] = lv.y; v[i*4+2] = lv.z; v[i*4+3] = lv.w;
    } else {
      bf16x4 lv = *(const bf16x4*)(rp + c);
      #pragma unroll
      for (int jj = 0; jj < 4; jj++) v[i*4+jj] = (float)lv[jj];
    }
  }
  float s = 0.f, sq = 0.f;
  #pragma unroll
  for (int k = 0; k < 12; k++) { s += v[k]; sq += v[k]*v[k]; }
  #pragma unroll
  for (int d = 1; d < 64; d <<= 1) { s += __shfl_xor(s, d); sq += __shfl_xor(sq, d); }
  float mean = s * (1.f/768.f);
  float rstd = rsqrtf(sq * (1.f/768.f) - mean*mean + 1e-5f);
  #pragma unroll
  for (int i = 0; i < 3; i++) {
    int c = i * 256 + lane * 4;
    float4 gv = *(const float4*)(g + c);
    float4 bv = *(const float4*)(be + c);
    bf16x4 o;
    o[0] = (__bf16)((v[i*4+0]-mean)*rstd*gv.x + bv.x);
    o[1] = (__bf16)((v[i*4+1]-mean)*rstd*gv.y + bv.y);
    o[2] = (__bf16)((v[i*4+2]-mean)*rstd*gv.z + bv.z);
    o[3] = (__bf16)((v[i*4+3]-mean)*rstd*gv.w + bv.w);
    *(bf16x4*)(out + (size_t)row*768 + c) = o;
  }
}

// ---------------- merged weight packing: packcat + 3x packT in one launch ----------------
__device__ __forceinline__ void packT_body(const float* __restrict__ src, __bf16* __restrict__ dst,
                                           int N, int K, int idx) {
  int K8 = K >> 3;
  int n = idx / K8, k0 = (idx % K8) * 8;
  bfrag o;
  #pragma unroll
  for (int i = 0; i < 8; i++) o[i] = (__bf16)src[(size_t)(k0+i)*N + n];
  *(bfrag*)&dst[(size_t)n*K + k0] = o;
}

__global__ __launch_bounds__(256) void k_packall(
    const float* __restrict__ Wq, const float* __restrict__ Wk,
    const float* __restrict__ Wv, const float* __restrict__ Wqv,
    const float* __restrict__ bq, const float* __restrict__ bk,
    const float* __restrict__ bv, const float* __restrict__ bqv,
    const float* __restrict__ Wf, const float* __restrict__ W1, const float* __restrict__ W2,
    __bf16* __restrict__ Wcat, float* __restrict__ bcat,
    __bf16* __restrict__ WfT, __bf16* __restrict__ W1T, __bf16* __restrict__ W2T) {
  int bidx = blockIdx.x;
  if (bidx < 912) {
    int idx = bidx * 256 + threadIdx.x;
    if (idx >= 2432 * 96) return;
    int n = idx / 96, k0 = (idx % 96) * 8;
    const float* src; int col, sN; float sc = 1.f;
    if (n < 768)       { src = Wq;  col = n;        sN = 768; sc = 0.125f; }
    else if (n < 1536) { src = Wk;  col = n - 768;  sN = 768; }
    else if (n < 2048) { src = Wv;  col = n - 1536; sN = 512; }
    else               { src = Wqv; col = n - 2048; sN = 384; sc = 0.1767766952966369f; }
    bfrag o;
    #pragma unroll
    for (int i = 0; i < 8; i++) o[i] = (__bf16)(src[(size_t)(k0+i)*sN + col] * sc);
    *(bfrag*)&Wcat[(size_t)n*768 + k0] = o;
    if (k0 == 0) {
      float bb;
      if (n < 768) bb = bq[col]*0.125f;
      else if (n < 1536) bb = bk[col];
      else if (n < 2048) bb = bv[col];
      else bb = bqv[col]*0.1767766952966369f;
      bcat[n] = bb;
    }
  } else if (bidx < 1200) {
    int idx = (bidx - 912) * 256 + threadIdx.x;
    if (idx < 768*96) packT_body(Wf, WfT, 768, 768, idx);
  } else if (bidx < 1776) {
    int idx = (bidx - 1200) * 256 + threadIdx.x;
    if (idx < 1536*96) packT_body(W1, W1T, 1536, 768, idx);
  } else {
    int idx = (bidx - 1776) * 256 + threadIdx.x;
    if (idx < 768*192) packT_body(W2, W2T, 768, 1536, idx);
  }
}

// ---------------- GEMM: [8192,KD]bf16 @ Bt[N,KD]bf16 -> epilogues ----------------
template<int KD, int EPI>
__global__ __launch_bounds__(256, 3) void k_gemm(const __bf16* __restrict__ A,
    const __bf16* __restrict__ Bt, const float* __restrict__ bias,
    const float* __restrict__ resf, const __bf16* __restrict__ resb,
    void* __restrict__ Cout, int N) {
  __shared__ __bf16 Al[2][128*32];
  __shared__ __bf16 Bl[2][128*32];
  // bijective XCD swizzle on m-tiles (gridDim.x == 64 == 8*8)
  const int bx = (blockIdx.x & 7) * 8 + (blockIdx.x >> 3);
  const int m0 = bx * 128, n0 = blockIdx.y * 128;
  const int tid = threadIdx.x, lane = tid & 63, w = tid >> 6;
  const int wm = (w >> 1) * 64, wn = (w & 1) * 64;
  const int srow = lane >> 2, skoff = (lane & 3) * 8;
  const int l15 = lane & 15, lg = lane >> 4;
  f32x4 acc[4][4];
  #pragma unroll
  for (int i = 0; i < 4; i++)
    #pragma unroll
    for (int j = 0; j < 4; j++) acc[i][j] = (f32x4){0.f,0.f,0.f,0.f};
  const int NT = KD / 32;
  auto stage = [&](int buf, int k0) {
    #pragma unroll
    for (int i = 0; i < 2; i++) {
      int c = w * 2 + i;
      gl_lds16(A  + (size_t)(m0 + c*16 + srow) * KD + k0 + skoff, &Al[buf][c*512]);
      gl_lds16(Bt + (size_t)(n0 + c*16 + srow) * KD + k0 + skoff, &Bl[buf][c*512]);
    }
  };
  stage(0, 0);
  __syncthreads();
  for (int t = 0; t < NT; t++) {
    int buf = t & 1;
    if (t + 1 < NT) stage(buf ^ 1, (t + 1) * 32);
    bfrag af[4], bfm[4];
    #pragma unroll
    for (int f = 0; f < 4; f++) {
      af[f]  = *(const bfrag*)&Al[buf][(wm + f*16 + l15)*32 + lg*8];
      bfm[f] = *(const bfrag*)&Bl[buf][(wn + f*16 + l15)*32 + lg*8];
    }
    #pragma unroll
    for (int i = 0; i < 4; i++)
      #pragma unroll
      for (int j = 0; j < 4; j++)
        acc[i][j] = MFMA(af[i], bfm[j], acc[i][j]);
    __syncthreads();
  }
  #pragma unroll
  for (int i = 0; i < 4; i++) {
    int row0 = m0 + wm + i*16 + lg*4;
    #pragma unroll
    for (int j = 0; j < 4; j++) {
      int col = n0 + wn + j*16 + l15;
      float bv = bias[col];
      #pragma unroll
      for (int q = 0; q < 4; q++) {
        size_t r = (size_t)(row0 + q);
        float v = acc[i][j][q] + bv;
        if (EPI == 0)      ((__bf16*)Cout)[r*N + col] = (__bf16)v;
        else if (EPI == 1) { v += resf[r*N + col]; ((__bf16*)Cout)[r*N + col] = (__bf16)v; }
        else if (EPI == 2) ((__bf16*)Cout)[r*N + col] = (__bf16)fmaxf(v, 0.f);
        else               { v += (float)resb[r*N + col]; ((float*)Cout)[r*N + col] = v; }
      }
    }
  }
}

// ---------------- V transpose + fused qdot ----------------
__global__ __launch_bounds__(256) void k_vt(const __bf16* __restrict__ C, const float* __restrict__ Ws,
                                            const float* __restrict__ bs,
                                            __bf16* __restrict__ VT, float* __restrict__ qd) {
  int bid = blockIdx.x;
  int b = bid >> 8, dt = (bid >> 5) & 7, kt = bid & 31;
  __shared__ __bf16 tile[64][72];
  int tid = threadIdx.x;
  int r = tid >> 3, c0 = (tid & 7) * 8;
  #pragma unroll
  for (int p = 0; p < 2; p++) {
    int rr = r + p * 32;
    bfrag v = *(const bfrag*)&C[(size_t)(b*2048 + kt*64 + rr)*NC + 1536 + dt*64 + c0];
    *(bfrag*)&tile[rr][c0] = v;
  }
  __syncthreads();
  #pragma unroll
  for (int p = 0; p < 2; p++) {
    int d = r + p * 32;
    bfrag o;
    #pragma unroll
    for (int i = 0; i < 8; i++) o[i] = tile[c0 + i][d];
    *(bfrag*)&VT[((size_t)b*512 + dt*64 + d)*2048 + kt*64 + c0] = o;
  }
  // fused qdot: dt==0 blocks cover rows kt*64..+64 (64 rows x 12 h = 768 dots)
  if (dt == 0) {
    float bsv = bs[0];
    #pragma unroll
    for (int p = 0; p < 3; p++) {
      int idx = p * 256 + tid;   // < 768
      int rl = idx / 12, h = idx % 12;
      size_t srow = (size_t)(b*2048 + kt*64 + rl);
      const __bf16* qp = &C[srow*NC + 2048 + h*32];
      float s = bsv;
      #pragma unroll
      for (int c = 0; c < 4; c++) {
        bfrag v = *(const bfrag*)(qp + c*8);
        #pragma unroll
        for (int i = 0; i < 8; i++) s += (float)v[i] * Ws[c*8 + i];
      }
      qd[srow*12 + h] = s;
    }
  }
}

// ---------------- fused flash attention + compositional mixing ----------------
// R22: R21 with the kbuf slot arithmetic FIXED (R21 halved the strides: one K
// tile is 4096 bf16 = 8KB, each wave stages 512 elements). 2 tiles per barrier
// region (16 barriers); P in 4 slots of [128][128B] (bank-friendly stride kept);
// tiles sequential within region (register footprint = R20).
// Races: qk in iter m writes P slots (2m+2)&3,(2m+3)&3; PV(m) reads (2m)&3,
// (2m+1)&3 — disjoint. K slot = t&3: DMA in iter m overwrites slots whose
// readers (qk in m-1) finished pre-barrier(m); drained by barrier(m+1).
// LDS map (loop):
//   [0,65536)       Pl 4 slots x [128][128B swizzled]
//   [65536,98304)   kbuf 4 slots x 8192B
//   [98304,102400)  wlb [128][8] f32  (comp, then rule weights)
// Epilogue: rbuf [8][32][64]bf16 (32KB) overlaps Pl; 4 static chunks of 32 rows.
__global__ __launch_bounds__(512, 2) void k_attn(const __bf16* __restrict__ C,
    const __bf16* __restrict__ VT, const float* __restrict__ Ws,
    const float* __restrict__ qdot, __bf16* __restrict__ attno, float* __restrict__ prevout) {
  __shared__ __align__(16) char smem[102400];
  __bf16* Pl   = (__bf16*)(smem);
  __bf16* kbuf = (__bf16*)(smem + 65536);
  float*  wlb  = (float*)(smem + 98304);
  __bf16* rbuf = (__bf16*)(smem);

  const int tid = threadIdx.x, lane = tid & 63, wid = tid >> 6;
  const int l15 = lane & 15, lg = lane >> 4;
  // bijective XCD swizzle: 768 = 8 * 96
  const int bid = (blockIdx.x & 7) * 96 + (blockIdx.x >> 3);
  const int b = bid / 192, rem = bid % 192, h = rem / 16, qb = rem % 16;
  const int q0 = qb * 128;

  const __bf16* VTb = VT + (size_t)b * 512 * 2048;
  // per-lane pre-swizzled K source in C (tile t adds t*64 rows)
  const int kkey = tid >> 3, kch = tid & 7;
  const __bf16* Ksrc0 = C + (size_t)(b*2048 + kkey)*NC + 768 + h*64 + ((kch ^ (kkey & 7)) * 8);

  auto stageK = [&](int t) {
    gl_lds16(Ksrc0 + (size_t)t * 64 * NC, kbuf + (t & 3)*4096 + (size_t)wid*512);
  };

  const __bf16* Qbase = C + (size_t)(b*2048 + q0 + wid*16 + l15)*NC + h*64 + lg*8;
  bfrag qf0 = *(const bfrag*)(Qbase);
  bfrag qf1 = *(const bfrag*)(Qbase + 32);

  f32x4 accv[8][4];
  #pragma unroll
  for (int i = 0; i < 8; i++)
    #pragma unroll
    for (int j = 0; j < 4; j++) accv[i][j] = (f32x4){0.f,0.f,0.f,0.f};
  float lsc = 0.f;   // running sum for row l15 over this thread's keys

  // Swapped QK^T + no-max softmax + packed P-write for tile tn (P slot tn&3).
  auto qk_phase = [&](int tn) {
    const __bf16* kb_ = kbuf + (tn & 3) * 4096;
    f32x4 s[4];
    #pragma unroll
    for (int cf = 0; cf < 4; cf++) s[cf] = (f32x4){0.f,0.f,0.f,0.f};
    #pragma unroll
    for (int cf = 0; cf < 4; cf++) {
      int key = cf*16 + l15, swz = key & 7;
      bfrag ka  = *(const bfrag*)(kb_ + key*64 + ((lg     ^ swz) * 8));
      bfrag kb2 = *(const bfrag*)(kb_ + key*64 + (((lg+4) ^ swz) * 8));
      s[cf] = MFMA(ka, qf0, s[cf]);
      s[cf] = MFMA(kb2, qf1, s[cf]);
    }
    int row = wid*16 + l15;
    char* base = (char*)Pl + (tn & 3)*16384 + row*128;
    int swz = (row & 7) << 4;
    #pragma unroll
    for (int cf = 0; cf < 4; cf++) {
      float p0 = fexp2(s[cf][0] * 1.44269504f);
      float p1 = fexp2(s[cf][1] * 1.44269504f);
      float p2 = fexp2(s[cf][2] * 1.44269504f);
      float p3 = fexp2(s[cf][3] * 1.44269504f);
      lsc += (p0 + p1) + (p2 + p3);
      uint2 pk;
      pk.x = cvtpk(p0, p1);
      pk.y = cvtpk(p2, p3);
      *(uint2*)(base + ((cf*32 + lg*8) ^ swz)) = pk;
    }
  };
  // PV for tile t: all 128 rows x own 64 cols (vb loaded inline)
  auto pv_tile = [&](int t) {
    const int k0 = t * 64, ps = t & 3;
    bfrag vb[4][2];
    #pragma unroll
    for (int cf = 0; cf < 4; cf++) {
      const __bf16* vp = VTb + (size_t)(wid*64 + cf*16 + l15)*2048 + k0 + lg*8;
      vb[cf][0] = *(const bfrag*)(vp);
      vb[cf][1] = *(const bfrag*)(vp + 32);
    }
    #pragma unroll
    for (int rf = 0; rf < 8; rf++) {
      int prow = rf*16 + l15;
      int swz = (prow & 7) << 4;
      const char* pbase = (const char*)Pl + ps*16384 + prow*128;
      bfrag pa0 = *(const bfrag*)(pbase + ((lg*16) ^ swz));
      bfrag pa1 = *(const bfrag*)(pbase + ((64 + lg*16) ^ swz));
      #pragma unroll
      for (int cf = 0; cf < 4; cf++) {
        accv[rf][cf] = MFMA(pa0, vb[cf][0], accv[rf][cf]);
        accv[rf][cf] = MFMA(pa1, vb[cf][1], accv[rf][cf]);
      }
    }
  };

  // prologue: stage K 0,1; barrier; P(0),P(1); stage K 2,3
  stageK(0); stageK(1);
  __syncthreads();
  qk_phase(0);
  qk_phase(1);
  stageK(2); stageK(3);

  for (int m = 0; m < 16; m++) {
    __syncthreads();   // P(2m),P(2m+1) visible; K(2m+2),(2m+3) staged
    if (m + 2 < 16) { stageK(2*m + 4); stageK(2*m + 5); }
    if (m < 15) qk_phase(2*m + 2);
    pv_tile(2*m);
    if (m < 15) qk_phase(2*m + 3);
    pv_tile(2*m + 1);
  }
  // ---- epilogue ----
  // lf for row l15: sum lsc over the 4 lanes sharing l15 (xor 16, 32)
  float lfall = lsc;
  lfall += __shfl_xor(lfall, 16);
  lfall += __shfl_xor(lfall, 32);
  float lf[4];
  #pragma unroll
  for (int j = 0; j < 4; j++) lf[j] = __shfl(lfall, lg*4 + j);   // row wid*16+lg*4+j

  // comp[row][r=wid] = sum_d accv[row][d] * ws_o[d], d = cf*16+l15
  {
    float wso = Ws[32 + l15];
    float wso1 = Ws[32 + 16 + l15];
    float wso2 = Ws[32 + 32 + l15];
    float wso3 = Ws[32 + 48 + l15];
    #pragma unroll
    for (int rf = 0; rf < 8; rf++) {
      #pragma unroll
      for (int j = 0; j < 4; j++) {
        float cj = accv[rf][0][j]*wso + accv[rf][1][j]*wso1
                 + accv[rf][2][j]*wso2 + accv[rf][3][j]*wso3;
        cj += __shfl_xor(cj, 1); cj += __shfl_xor(cj, 2);
        cj += __shfl_xor(cj, 4); cj += __shfl_xor(cj, 8);
        if (l15 == 0) wlb[(rf*16 + lg*4 + j)*8 + wid] = cj;   // unnormalized comp
      }
    }
  }
  __syncthreads();
  // rule softmax per own rows; read comp from LDS, write wp back to same slots
  {
    int rowg = b*2048 + q0 + wid*16 + lg*4;
    float cmp[4];
    #pragma unroll
    for (int j = 0; j < 4; j++) {
      float qdv = qdot[(size_t)(rowg + j)*12 + h];
      float cv = (l15 < 8) ? wlb[(wid*16 + lg*4 + j)*8 + l15] : 0.f;
      cmp[j] = (l15 < 8) ? (cv / lf[j] + qdv) : -INFINITY;
      if (l15 < 8) prevout[((size_t)(rowg + j)*12 + h)*8 + l15] = cmp[j];
    }
    #pragma unroll
    for (int j = 0; j < 4; j++) {
      float rm = cmp[j];
      rm = fmaxf(rm, __shfl_xor(rm, 1));
      rm = fmaxf(rm, __shfl_xor(rm, 2));
      rm = fmaxf(rm, __shfl_xor(rm, 4));
      float e = exp2f((cmp[j] - rm) * 1.44269504f);
      float rs = e;
      rs += __shfl_xor(rs, 1); rs += __shfl_xor(rs, 2); rs += __shfl_xor(rs, 4);
      float wp = e / (rs * lf[j]);
      if (l15 < 8) wlb[(wid*16 + lg*4 + j)*8 + l15] = wp;   // same lane-slot: safe
    }
  }
  __syncthreads();
  // chunked r-reduction: 4 STATIC chunks of 32 rows; rbuf [8][32][64]bf16 overlaps Pl
  #pragma unroll
  for (int c = 0; c < 4; c++) {
    #pragma unroll
    for (int rr = 0; rr < 2; rr++) {
      int rf = c*2 + rr;   // compile-time: accv stays in registers
      #pragma unroll
      for (int j = 0; j < 4; j++) {
        int row = rf*16 + lg*4 + j;
        int lrow = row - c*32;
        float wp = wlb[row*8 + wid];
        #pragma unroll
        for (int cf = 0; cf < 4; cf++)
          rbuf[((size_t)wid*32 + lrow)*64 + cf*16 + l15] = (__bf16)(accv[rf][cf][j] * wp);
      }
    }
    __syncthreads();
    {
      int row32 = tid >> 4, dc = (tid & 15) * 4;
      float os[4] = {0,0,0,0};
      #pragma unroll
      for (int r = 0; r < 8; r++) {
        bf16x4 v = *(const bf16x4*)&rbuf[((size_t)r*32 + row32)*64 + dc];
        #pragma unroll
        for (int i = 0; i < 4; i++) os[i] += (float)v[i];
      }
      int grow = c*32 + row32;
      bf16x4 ov;
      #pragma unroll
      for (int i = 0; i < 4; i++) ov[i] = (__bf16)os[i];
      *(bf16x4*)&attno[(size_t)(b*2048 + q0 + grow)*768 + h*64 + dc] = ov;
    }
    if (c < 3) __syncthreads();
  }
}

// ---------------- launch ----------------
extern "C" void kernel_launch(void* const* d_in, const int* in_sizes, int n_in,
                              void* d_out, int out_size, void* d_ws, size_t ws_size,
                              hipStream_t stream) {
  (void)in_sizes; (void)n_in; (void)out_size; (void)ws_size;
  const float* x   = (const float*)d_in[0];
  const float* Wq  = (const float*)d_in[1];
  const float* bq  = (const float*)d_in[2];
  const float* Wk  = (const float*)d_in[3];
  const float* bk  = (const float*)d_in[4];
  const float* Wv  = (const float*)d_in[5];
  const float* bv  = (const float*)d_in[6];
  const float* Wqv = (const float*)d_in[7];
  const float* bqv = (const float*)d_in[8];
  const float* Ws  = (const float*)d_in[9];
  const float* bs  = (const float*)d_in[10];
  const float* Wf  = (const float*)d_in[11];
  const float* bfp = (const float*)d_in[12];
  const float* W1  = (const float*)d_in[13];
  const float* b1  = (const float*)d_in[14];
  const float* W2  = (const float*)d_in[15];
  const float* b2  = (const float*)d_in[16];
  const float* g1  = (const float*)d_in[17];
  const float* be1 = (const float*)d_in[18];
  const float* g2  = (const float*)d_in[19];
  const float* be2 = (const float*)d_in[20];

  char* ws = (char*)d_ws;
  __bf16* Cbuf  = (__bf16*)(ws + OFF_C);
  __bf16* xn    = (__bf16*)(ws + OFF_XN);
  __bf16* VTb   = (__bf16*)(ws + OFF_VT);
  float*  qdotb = (float*)(ws + OFF_QDOT);
  __bf16* Wcat  = (__bf16*)(ws + OFF_WCAT);
  float*  bcat  = (float*)(ws + OFF_BCAT);
  __bf16* WfT   = (__bf16*)(ws + OFF_WFT);
  __bf16* W1T   = (__bf16*)(ws + OFF_W1T);
  __bf16* W2T   = (__bf16*)(ws + OFF_W2T);
  __bf16* attno = (__bf16*)(ws + OFF_ATTNO);
  __bf16* out1  = (__bf16*)(ws + OFF_OUT1);
  __bf16* onb   = (__bf16*)(ws + OFF_ON);
  __bf16* h1    = (__bf16*)(ws + OFF_H1);
  float*  outp  = (float*)d_out;
  float*  prevp = outp + 6291456;   // 4*2048*768

  k_ln<float><<<2048, 256, 0, stream>>>(x, g1, be1, xn);
  k_packall<<<2352, 256, 0, stream>>>(Wq, Wk, Wv, Wqv, bq, bk, bv, bqv,
                                      Wf, W1, W2, Wcat, bcat, WfT, W1T, W2T);

  k_gemm<768, 0><<<dim3(64, 19), 256, 0, stream>>>(xn, Wcat, bcat, nullptr, nullptr, Cbuf, NC);

  k_vt<<<1024, 256, 0, stream>>>(Cbuf, Ws, bs, VTb, qdotb);

  k_attn<<<768, 512, 0, stream>>>(Cbuf, VTb, Ws, qdotb, attno, prevp);

  k_gemm<768, 1><<<dim3(64, 6), 256, 0, stream>>>(attno, WfT, bfp, x, nullptr, out1, 768);
  k_ln<__bf16><<<2048, 256, 0, stream>>>(out1, g2, be2, onb);
  k_gemm<768, 2><<<dim3(64, 12), 256, 0, stream>>>(onb, W1T, b1, nullptr, nullptr, h1, 1536);
  k_gemm<1536, 3><<<dim3(64, 6), 256, 0, stream>>>(h1, W2T, b2, nullptr, out1, outp, 768);
}

// Round 23
// 468.542 us; speedup vs baseline: 1.1495x; 1.0080x over previous
//
#include <hip/hip_runtime.h>
#include <hip/hip_bf16.h>

// ---------------- types ----------------
typedef __bf16 bfrag  __attribute__((ext_vector_type(8)));  // 8 bf16 = 4 VGPR (MFMA A/B frag)
typedef __bf16 bf16x4 __attribute__((ext_vector_type(4)));
typedef float  f32x4  __attribute__((ext_vector_type(4)));

#define MFMA(a,b,c) __builtin_amdgcn_mfma_f32_16x16x32_bf16(a,b,c,0,0,0)

__device__ __forceinline__ void gl_lds16(const void* g, void* l) {
  __builtin_amdgcn_global_load_lds((const __attribute__((address_space(1))) void*)g,
                                   (__attribute__((address_space(3))) void*)l, 16, 0, 0);
}
// raw 2^x (inputs are small/normal here; avoids OCML guard path)
__device__ __forceinline__ float fexp2(float x) {
  float r;
  asm("v_exp_f32 %0, %1" : "=v"(r) : "v"(x));
  return r;
}
// pack two f32 -> (bf16,bf16) in one u32
__device__ __forceinline__ unsigned cvtpk(float lo, float hi) {
  unsigned r;
  asm("v_cvt_pk_bf16_f32 %0, %1, %2" : "=v"(r) : "v"(lo), "v"(hi));
  return r;
}

// ---------------- problem dims ----------------
// B=4 S=2048 DIM=768 H=12 HD=64 QK=32 R=8
// C (proj out) cols: q[0,768) k[768,1536) v[1536,2048) qv[2048,2432)
#define NC 2432

// ---------------- workspace layout (bytes) ----------------
#define OFF_C     ((size_t)0)           // bf16 [8192][2432]    39,845,888
#define OFF_VT    ((size_t)52428800)    // bf16 [4][512][2048]   8,388,608
#define OFF_QDOT  ((size_t)61079552)    // f32  [4][2048][12]      393,216
#define OFF_WCAT  ((size_t)61472768)    // bf16 [2432][768]      3,735,552
#define OFF_BCAT  ((size_t)65208320)    // f32  [2432]               9,728
#define OFF_WFT   ((size_t)65218048)    // bf16 [768][768]       1,179,648
#define OFF_W1T   ((size_t)66397696)    // bf16 [1536][768]      2,359,296
#define OFF_W2T   ((size_t)68756992)    // bf16 [768][1536]      2,359,296
#define OFF_ATTNO ((size_t)71116288)    // bf16 [8192][768]     12,582,912
#define OFF_XN    ((size_t)39845888)    // bf16 [8192][768]     12,582,912
// reuse (after attention, C/XN/VT dead):
#define OFF_OUT1  ((size_t)0)           // bf16 [8192][768]
#define OFF_ON    ((size_t)12582912)    // bf16 [8192][768]
#define OFF_H1    ((size_t)25165824)    // bf16 [8192][1536]

// ---------------- LayerNorm: wave per row (768 cols) ----------------
template<typename TIN>
__global__ __launch_bounds__(256) void k_ln(const TIN* __restrict__ in,
    const float* __restrict__ g, const float* __restrict__ be, __bf16* __restrict__ out) {
  int row  = blockIdx.x * 4 + (threadIdx.x >> 6);
  int lane = threadIdx.x & 63;
  const TIN* rp = in + (size_t)row * 768;
  float v[12];
  #pragma unroll
  for (int i = 0; i < 3; i++) {
    int c = i * 256 + lane * 4;
    if constexpr (sizeof(TIN) == 4) {
      float4 lv = *(const float4*)(rp + c);
      v[i*4+0] = lv.x; v[i*4+1] = lv.y; v[i*4+2] = lv.z; v[i*4+3] = lv.w;
    } else {
      bf16x4 lv = *(const bf16x4*)(rp + c);
      #pragma unroll
      for (int jj = 0; jj < 4; jj++) v[i*4+jj] = (float)lv[jj];
    }
  }
  float s = 0.f, sq = 0.f;
  #pragma unroll
  for (int k = 0; k < 12; k++) { s += v[k]; sq += v[k]*v[k]; }
  #pragma unroll
  for (int d = 1; d < 64; d <<= 1) { s += __shfl_xor(s, d); sq += __shfl_xor(sq, d); }
  float mean = s * (1.f/768.f);
  float rstd = rsqrtf(sq * (1.f/768.f) - mean*mean + 1e-5f);
  #pragma unroll
  for (int i = 0; i < 3; i++) {
    int c = i * 256 + lane * 4;
    float4 gv = *(const float4*)(g + c);
    float4 bv = *(const float4*)(be + c);
    bf16x4 o;
    o[0] = (__bf16)((v[i*4+0]-mean)*rstd*gv.x + bv.x);
    o[1] = (__bf16)((v[i*4+1]-mean)*rstd*gv.y + bv.y);
    o[2] = (__bf16)((v[i*4+2]-mean)*rstd*gv.z + bv.z);
    o[3] = (__bf16)((v[i*4+3]-mean)*rstd*gv.w + bv.w);
    *(bf16x4*)(out + (size_t)row*768 + c) = o;
  }
}

// ---------------- merged weight packing: packcat + 3x packT in one launch ----------------
__device__ __forceinline__ void packT_body(const float* __restrict__ src, __bf16* __restrict__ dst,
                                           int N, int K, int idx) {
  int K8 = K >> 3;
  int n = idx / K8, k0 = (idx % K8) * 8;
  bfrag o;
  #pragma unroll
  for (int i = 0; i < 8; i++) o[i] = (__bf16)src[(size_t)(k0+i)*N + n];
  *(bfrag*)&dst[(size_t)n*K + k0] = o;
}

__global__ __launch_bounds__(256) void k_packall(
    const float* __restrict__ Wq, const float* __restrict__ Wk,
    const float* __restrict__ Wv, const float* __restrict__ Wqv,
    const float* __restrict__ bq, const float* __restrict__ bk,
    const float* __restrict__ bv, const float* __restrict__ bqv,
    const float* __restrict__ Wf, const float* __restrict__ W1, const float* __restrict__ W2,
    __bf16* __restrict__ Wcat, float* __restrict__ bcat,
    __bf16* __restrict__ WfT, __bf16* __restrict__ W1T, __bf16* __restrict__ W2T) {
  int bidx = blockIdx.x;
  if (bidx < 912) {
    int idx = bidx * 256 + threadIdx.x;
    if (idx >= 2432 * 96) return;
    int n = idx / 96, k0 = (idx % 96) * 8;
    const float* src; int col, sN; float sc = 1.f;
    if (n < 768)       { src = Wq;  col = n;        sN = 768; sc = 0.125f; }
    else if (n < 1536) { src = Wk;  col = n - 768;  sN = 768; }
    else if (n < 2048) { src = Wv;  col = n - 1536; sN = 512; }
    else               { src = Wqv; col = n - 2048; sN = 384; sc = 0.1767766952966369f; }
    bfrag o;
    #pragma unroll
    for (int i = 0; i < 8; i++) o[i] = (__bf16)(src[(size_t)(k0+i)*sN + col] * sc);
    *(bfrag*)&Wcat[(size_t)n*768 + k0] = o;
    if (k0 == 0) {
      float bb;
      if (n < 768) bb = bq[col]*0.125f;
      else if (n < 1536) bb = bk[col];
      else if (n < 2048) bb = bv[col];
      else bb = bqv[col]*0.1767766952966369f;
      bcat[n] = bb;
    }
  } else if (bidx < 1200) {
    int idx = (bidx - 912) * 256 + threadIdx.x;
    if (idx < 768*96) packT_body(Wf, WfT, 768, 768, idx);
  } else if (bidx < 1776) {
    int idx = (bidx - 1200) * 256 + threadIdx.x;
    if (idx < 1536*96) packT_body(W1, W1T, 1536, 768, idx);
  } else {
    int idx = (bidx - 1776) * 256 + threadIdx.x;
    if (idx < 768*192) packT_body(W2, W2T, 768, 1536, idx);
  }
}

// ---------------- GEMM 128x128: [8192,KD]bf16 @ Bt[N,KD]bf16 -> epilogues ----------------
template<int KD, int EPI>
__global__ __launch_bounds__(256, 3) void k_gemm(const __bf16* __restrict__ A,
    const __bf16* __restrict__ Bt, const float* __restrict__ bias,
    const float* __restrict__ resf, const __bf16* __restrict__ resb,
    void* __restrict__ Cout, int N) {
  __shared__ __bf16 Al[2][128*32];
  __shared__ __bf16 Bl[2][128*32];
  // bijective XCD swizzle on m-tiles (gridDim.x == 64 == 8*8)
  const int bx = (blockIdx.x & 7) * 8 + (blockIdx.x >> 3);
  const int m0 = bx * 128, n0 = blockIdx.y * 128;
  const int tid = threadIdx.x, lane = tid & 63, w = tid >> 6;
  const int wm = (w >> 1) * 64, wn = (w & 1) * 64;
  const int srow = lane >> 2, skoff = (lane & 3) * 8;
  const int l15 = lane & 15, lg = lane >> 4;
  f32x4 acc[4][4];
  #pragma unroll
  for (int i = 0; i < 4; i++)
    #pragma unroll
    for (int j = 0; j < 4; j++) acc[i][j] = (f32x4){0.f,0.f,0.f,0.f};
  const int NT = KD / 32;
  auto stage = [&](int buf, int k0) {
    #pragma unroll
    for (int i = 0; i < 2; i++) {
      int c = w * 2 + i;
      gl_lds16(A  + (size_t)(m0 + c*16 + srow) * KD + k0 + skoff, &Al[buf][c*512]);
      gl_lds16(Bt + (size_t)(n0 + c*16 + srow) * KD + k0 + skoff, &Bl[buf][c*512]);
    }
  };
  stage(0, 0);
  __syncthreads();
  for (int t = 0; t < NT; t++) {
    int buf = t & 1;
    if (t + 1 < NT) stage(buf ^ 1, (t + 1) * 32);
    bfrag af[4], bfm[4];
    #pragma unroll
    for (int f = 0; f < 4; f++) {
      af[f]  = *(const bfrag*)&Al[buf][(wm + f*16 + l15)*32 + lg*8];
      bfm[f] = *(const bfrag*)&Bl[buf][(wn + f*16 + l15)*32 + lg*8];
    }
    #pragma unroll
    for (int i = 0; i < 4; i++)
      #pragma unroll
      for (int j = 0; j < 4; j++)
        acc[i][j] = MFMA(af[i], bfm[j], acc[i][j]);
    __syncthreads();
  }
  #pragma unroll
  for (int i = 0; i < 4; i++) {
    int row0 = m0 + wm + i*16 + lg*4;
    #pragma unroll
    for (int j = 0; j < 4; j++) {
      int col = n0 + wn + j*16 + l15;
      float bv = bias[col];
      #pragma unroll
      for (int q = 0; q < 4; q++) {
        size_t r = (size_t)(row0 + q);
        float v = acc[i][j][q] + bv;
        if (EPI == 0)      ((__bf16*)Cout)[r*N + col] = (__bf16)v;
        else if (EPI == 1) { v += resf[r*N + col]; ((__bf16*)Cout)[r*N + col] = (__bf16)v; }
        else if (EPI == 2) ((__bf16*)Cout)[r*N + col] = (__bf16)fmaxf(v, 0.f);
        else               { v += (float)resb[r*N + col]; ((float*)Cout)[r*N + col] = v; }
      }
    }
  }
}

// ---------------- GEMM 64x128: higher-occupancy variant for N=768 tail GEMMs ----------------
// 4 waves, acc[2][4]=32 f32/thread, LDS 24KB -> ~3+ blocks/CU (vs 1.5 for 128^2
// at grid 384): doubles resident waves on the latency-bound shallow-K GEMMs.
template<int KD, int EPI>
__global__ __launch_bounds__(256) void k_gemm64(const __bf16* __restrict__ A,
    const __bf16* __restrict__ Bt, const float* __restrict__ bias,
    const float* __restrict__ resf, const __bf16* __restrict__ resb,
    void* __restrict__ Cout, int N) {
  __shared__ __bf16 Al[2][64*32];
  __shared__ __bf16 Bl[2][128*32];
  // bijective XCD swizzle on m-tiles (gridDim.x == 128 == 8*16)
  const int bx = (blockIdx.x & 7) * 16 + (blockIdx.x >> 3);
  const int m0 = bx * 64, n0 = blockIdx.y * 128;
  const int tid = threadIdx.x, lane = tid & 63, w = tid >> 6;
  const int wm = (w >> 1) * 32, wn = (w & 1) * 64;
  const int srow = lane >> 2, skoff = (lane & 3) * 8;
  const int l15 = lane & 15, lg = lane >> 4;
  f32x4 acc[2][4];
  #pragma unroll
  for (int i = 0; i < 2; i++)
    #pragma unroll
    for (int j = 0; j < 4; j++) acc[i][j] = (f32x4){0.f,0.f,0.f,0.f};
  const int NT = KD / 32;
  auto stage = [&](int buf, int k0) {
    // A: 64 rows = 4 chunks of 16, one per wave
    gl_lds16(A + (size_t)(m0 + w*16 + srow) * KD + k0 + skoff, &Al[buf][w*512]);
    // B: 128 rows = 8 chunks of 16, two per wave
    #pragma unroll
    for (int i = 0; i < 2; i++) {
      int c = w * 2 + i;
      gl_lds16(Bt + (size_t)(n0 + c*16 + srow) * KD + k0 + skoff, &Bl[buf][c*512]);
    }
  };
  stage(0, 0);
  __syncthreads();
  for (int t = 0; t < NT; t++) {
    int buf = t & 1;
    if (t + 1 < NT) stage(buf ^ 1, (t + 1) * 32);
    bfrag af[2], bfm[4];
    #pragma unroll
    for (int f = 0; f < 2; f++)
      af[f] = *(const bfrag*)&Al[buf][(wm + f*16 + l15)*32 + lg*8];
    #pragma unroll
    for (int f = 0; f < 4; f++)
      bfm[f] = *(const bfrag*)&Bl[buf][(wn + f*16 + l15)*32 + lg*8];
    #pragma unroll
    for (int i = 0; i < 2; i++)
      #pragma unroll
      for (int j = 0; j < 4; j++)
        acc[i][j] = MFMA(af[i], bfm[j], acc[i][j]);
    __syncthreads();
  }
  #pragma unroll
  for (int i = 0; i < 2; i++) {
    int row0 = m0 + wm + i*16 + lg*4;
    #pragma unroll
    for (int j = 0; j < 4; j++) {
      int col = n0 + wn + j*16 + l15;
      float bv = bias[col];
      #pragma unroll
      for (int q = 0; q < 4; q++) {
        size_t r = (size_t)(row0 + q);
        float v = acc[i][j][q] + bv;
        if (EPI == 0)      ((__bf16*)Cout)[r*N + col] = (__bf16)v;
        else if (EPI == 1) { v += resf[r*N + col]; ((__bf16*)Cout)[r*N + col] = (__bf16)v; }
        else if (EPI == 2) ((__bf16*)Cout)[r*N + col] = (__bf16)fmaxf(v, 0.f);
        else               { v += (float)resb[r*N + col]; ((float*)Cout)[r*N + col] = v; }
      }
    }
  }
}

// ---------------- V transpose + fused qdot ----------------
__global__ __launch_bounds__(256) void k_vt(const __bf16* __restrict__ C, const float* __restrict__ Ws,
                                            const float* __restrict__ bs,
                                            __bf16* __restrict__ VT, float* __restrict__ qd) {
  int bid = blockIdx.x;
  int b = bid >> 8, dt = (bid >> 5) & 7, kt = bid & 31;
  __shared__ __bf16 tile[64][72];
  int tid = threadIdx.x;
  int r = tid >> 3, c0 = (tid & 7) * 8;
  #pragma unroll
  for (int p = 0; p < 2; p++) {
    int rr = r + p * 32;
    bfrag v = *(const bfrag*)&C[(size_t)(b*2048 + kt*64 + rr)*NC + 1536 + dt*64 + c0];
    *(bfrag*)&tile[rr][c0] = v;
  }
  __syncthreads();
  #pragma unroll
  for (int p = 0; p < 2; p++) {
    int d = r + p * 32;
    bfrag o;
    #pragma unroll
    for (int i = 0; i < 8; i++) o[i] = tile[c0 + i][d];
    *(bfrag*)&VT[((size_t)b*512 + dt*64 + d)*2048 + kt*64 + c0] = o;
  }
  // fused qdot: dt==0 blocks cover rows kt*64..+64 (64 rows x 12 h = 768 dots)
  if (dt == 0) {
    float bsv = bs[0];
    #pragma unroll
    for (int p = 0; p < 3; p++) {
      int idx = p * 256 + tid;   // < 768
      int rl = idx / 12, h = idx % 12;
      size_t srow = (size_t)(b*2048 + kt*64 + rl);
      const __bf16* qp = &C[srow*NC + 2048 + h*32];
      float s = bsv;
      #pragma unroll
      for (int c = 0; c < 4; c++) {
        bfrag v = *(const bfrag*)(qp + c*8);
        #pragma unroll
        for (int i = 0; i < 8; i++) s += (float)v[i] * Ws[c*8 + i];
      }
      qd[srow*12 + h] = s;
    }
  }
}

// ---------------- fused flash attention + compositional mixing (R22 final) ----------------
// 2 tiles per barrier region (16 barriers); P in 4 slots of [128][128B]; no-max
// softmax; swapped QK^T; packed P-writes; direct-from-C K staging; deferred
// epilogue comp; XCD swizzle; no setprio (lockstep waves).
// LDS map (loop):
//   [0,65536)       Pl 4 slots x [128][128B swizzled]
//   [65536,98304)   kbuf 4 slots x 8192B
//   [98304,102400)  wlb [128][8] f32  (comp, then rule weights)
// Epilogue: rbuf [8][32][64]bf16 (32KB) overlaps Pl; 4 static chunks of 32 rows.
__global__ __launch_bounds__(512, 2) void k_attn(const __bf16* __restrict__ C,
    const __bf16* __restrict__ VT, const float* __restrict__ Ws,
    const float* __restrict__ qdot, __bf16* __restrict__ attno, float* __restrict__ prevout) {
  __shared__ __align__(16) char smem[102400];
  __bf16* Pl   = (__bf16*)(smem);
  __bf16* kbuf = (__bf16*)(smem + 65536);
  float*  wlb  = (float*)(smem + 98304);
  __bf16* rbuf = (__bf16*)(smem);

  const int tid = threadIdx.x, lane = tid & 63, wid = tid >> 6;
  const int l15 = lane & 15, lg = lane >> 4;
  // bijective XCD swizzle: 768 = 8 * 96
  const int bid = (blockIdx.x & 7) * 96 + (blockIdx.x >> 3);
  const int b = bid / 192, rem = bid % 192, h = rem / 16, qb = rem % 16;
  const int q0 = qb * 128;

  const __bf16* VTb = VT + (size_t)b * 512 * 2048;
  // per-lane pre-swizzled K source in C (tile t adds t*64 rows)
  const int kkey = tid >> 3, kch = tid & 7;
  const __bf16* Ksrc0 = C + (size_t)(b*2048 + kkey)*NC + 768 + h*64 + ((kch ^ (kkey & 7)) * 8);

  auto stageK = [&](int t) {
    gl_lds16(Ksrc0 + (size_t)t * 64 * NC, kbuf + (t & 3)*4096 + (size_t)wid*512);
  };

  const __bf16* Qbase = C + (size_t)(b*2048 + q0 + wid*16 + l15)*NC + h*64 + lg*8;
  bfrag qf0 = *(const bfrag*)(Qbase);
  bfrag qf1 = *(const bfrag*)(Qbase + 32);

  f32x4 accv[8][4];
  #pragma unroll
  for (int i = 0; i < 8; i++)
    #pragma unroll
    for (int j = 0; j < 4; j++) accv[i][j] = (f32x4){0.f,0.f,0.f,0.f};
  float lsc = 0.f;   // running sum for row l15 over this thread's keys

  // Swapped QK^T + no-max softmax + packed P-write for tile tn (P slot tn&3).
  auto qk_phase = [&](int tn) {
    const __bf16* kb_ = kbuf + (tn & 3) * 4096;
    f32x4 s[4];
    #pragma unroll
    for (int cf = 0; cf < 4; cf++) s[cf] = (f32x4){0.f,0.f,0.f,0.f};
    #pragma unroll
    for (int cf = 0; cf < 4; cf++) {
      int key = cf*16 + l15, swz = key & 7;
      bfrag ka  = *(const bfrag*)(kb_ + key*64 + ((lg     ^ swz) * 8));
      bfrag kb2 = *(const bfrag*)(kb_ + key*64 + (((lg+4) ^ swz) * 8));
      s[cf] = MFMA(ka, qf0, s[cf]);
      s[cf] = MFMA(kb2, qf1, s[cf]);
    }
    int row = wid*16 + l15;
    char* base = (char*)Pl + (tn & 3)*16384 + row*128;
    int swz = (row & 7) << 4;
    #pragma unroll
    for (int cf = 0; cf < 4; cf++) {
      float p0 = fexp2(s[cf][0] * 1.44269504f);
      float p1 = fexp2(s[cf][1] * 1.44269504f);
      float p2 = fexp2(s[cf][2] * 1.44269504f);
      float p3 = fexp2(s[cf][3] * 1.44269504f);
      lsc += (p0 + p1) + (p2 + p3);
      uint2 pk;
      pk.x = cvtpk(p0, p1);
      pk.y = cvtpk(p2, p3);
      *(uint2*)(base + ((cf*32 + lg*8) ^ swz)) = pk;
    }
  };
  // PV for tile t: all 128 rows x own 64 cols (vb loaded inline)
  auto pv_tile = [&](int t) {
    const int k0 = t * 64, ps = t & 3;
    bfrag vb[4][2];
    #pragma unroll
    for (int cf = 0; cf < 4; cf++) {
      const __bf16* vp = VTb + (size_t)(wid*64 + cf*16 + l15)*2048 + k0 + lg*8;
      vb[cf][0] = *(const bfrag*)(vp);
      vb[cf][1] = *(const bfrag*)(vp + 32);
    }
    #pragma unroll
    for (int rf = 0; rf < 8; rf++) {
      int prow = rf*16 + l15;
      int swz = (prow & 7) << 4;
      const char* pbase = (const char*)Pl + ps*16384 + prow*128;
      bfrag pa0 = *(const bfrag*)(pbase + ((lg*16) ^ swz));
      bfrag pa1 = *(const bfrag*)(pbase + ((64 + lg*16) ^ swz));
      #pragma unroll
      for (int cf = 0; cf < 4; cf++) {
        accv[rf][cf] = MFMA(pa0, vb[cf][0], accv[rf][cf]);
        accv[rf][cf] = MFMA(pa1, vb[cf][1], accv[rf][cf]);
      }
    }
  };

  // prologue: stage K 0,1; barrier; P(0),P(1); stage K 2,3
  stageK(0); stageK(1);
  __syncthreads();
  qk_phase(0);
  qk_phase(1);
  stageK(2); stageK(3);

  for (int m = 0; m < 16; m++) {
    __syncthreads();   // P(2m),P(2m+1) visible; K(2m+2),(2m+3) staged
    if (m + 2 < 16) { stageK(2*m + 4); stageK(2*m + 5); }
    if (m < 15) qk_phase(2*m + 2);
    pv_tile(2*m);
    if (m < 15) qk_phase(2*m + 3);
    pv_tile(2*m + 1);
  }
  // ---- epilogue ----
  // lf for row l15: sum lsc over the 4 lanes sharing l15 (xor 16, 32)
  float lfall = lsc;
  lfall += __shfl_xor(lfall, 16);
  lfall += __shfl_xor(lfall, 32);
  float lf[4];
  #pragma unroll
  for (int j = 0; j < 4; j++) lf[j] = __shfl(lfall, lg*4 + j);   // row wid*16+lg*4+j

  // comp[row][r=wid] = sum_d accv[row][d] * ws_o[d], d = cf*16+l15
  {
    float wso = Ws[32 + l15];
    float wso1 = Ws[32 + 16 + l15];
    float wso2 = Ws[32 + 32 + l15];
    float wso3 = Ws[32 + 48 + l15];
    #pragma unroll
    for (int rf = 0; rf < 8; rf++) {
      #pragma unroll
      for (int j = 0; j < 4; j++) {
        float cj = accv[rf][0][j]*wso + accv[rf][1][j]*wso1
                 + accv[rf][2][j]*wso2 + accv[rf][3][j]*wso3;
        cj += __shfl_xor(cj, 1); cj += __shfl_xor(cj, 2);
        cj += __shfl_xor(cj, 4); cj += __shfl_xor(cj, 8);
        if (l15 == 0) wlb[(rf*16 + lg*4 + j)*8 + wid] = cj;   // unnormalized comp
      }
    }
  }
  __syncthreads();
  // rule softmax per own rows; read comp from LDS, write wp back to same slots
  {
    int rowg = b*2048 + q0 + wid*16 + lg*4;
    float cmp[4];
    #pragma unroll
    for (int j = 0; j < 4; j++) {
      float qdv = qdot[(size_t)(rowg + j)*12 + h];
      float cv = (l15 < 8) ? wlb[(wid*16 + lg*4 + j)*8 + l15] : 0.f;
      cmp[j] = (l15 < 8) ? (cv / lf[j] + qdv) : -INFINITY;
      if (l15 < 8) prevout[((size_t)(rowg + j)*12 + h)*8 + l15] = cmp[j];
    }
    #pragma unroll
    for (int j = 0; j < 4; j++) {
      float rm = cmp[j];
      rm = fmaxf(rm, __shfl_xor(rm, 1));
      rm = fmaxf(rm, __shfl_xor(rm, 2));
      rm = fmaxf(rm, __shfl_xor(rm, 4));
      float e = exp2f((cmp[j] - rm) * 1.44269504f);
      float rs = e;
      rs += __shfl_xor(rs, 1); rs += __shfl_xor(rs, 2); rs += __shfl_xor(rs, 4);
      float wp = e / (rs * lf[j]);
      if (l15 < 8) wlb[(wid*16 + lg*4 + j)*8 + l15] = wp;   // same lane-slot: safe
    }
  }
  __syncthreads();
  // chunked r-reduction: 4 STATIC chunks of 32 rows; rbuf [8][32][64]bf16 overlaps Pl
  #pragma unroll
  for (int c = 0; c < 4; c++) {
    #pragma unroll
    for (int rr = 0; rr < 2; rr++) {
      int rf = c*2 + rr;   // compile-time: accv stays in registers
      #pragma unroll
      for (int j = 0; j < 4; j++) {
        int row = rf*16 + lg*4 + j;
        int lrow = row - c*32;
        float wp = wlb[row*8 + wid];
        #pragma unroll
        for (int cf = 0; cf < 4; cf++)
          rbuf[((size_t)wid*32 + lrow)*64 + cf*16 + l15] = (__bf16)(accv[rf][cf][j] * wp);
      }
    }
    __syncthreads();
    {
      int row32 = tid >> 4, dc = (tid & 15) * 4;
      float os[4] = {0,0,0,0};
      #pragma unroll
      for (int r = 0; r < 8; r++) {
        bf16x4 v = *(const bf16x4*)&rbuf[((size_t)r*32 + row32)*64 + dc];
        #pragma unroll
        for (int i = 0; i < 4; i++) os[i] += (float)v[i];
      }
      int grow = c*32 + row32;
      bf16x4 ov;
      #pragma unroll
      for (int i = 0; i < 4; i++) ov[i] = (__bf16)os[i];
      *(bf16x4*)&attno[(size_t)(b*2048 + q0 + grow)*768 + h*64 + dc] = ov;
    }
    if (c < 3) __syncthreads();
  }
}

// ---------------- launch ----------------
extern "C" void kernel_launch(void* const* d_in, const int* in_sizes, int n_in,
                              void* d_out, int out_size, void* d_ws, size_t ws_size,
                              hipStream_t stream) {
  (void)in_sizes; (void)n_in; (void)out_size; (void)ws_size;
  const float* x   = (const float*)d_in[0];
  const float* Wq  = (const float*)d_in[1];
  const float* bq  = (const float*)d_in[2];
  const float* Wk  = (const float*)d_in[3];
  const float* bk  = (const float*)d_in[4];
  const float* Wv  = (const float*)d_in[5];
  const float* bv  = (const float*)d_in[6];
  const float* Wqv = (const float*)d_in[7];
  const float* bqv = (const float*)d_in[8];
  const float* Ws  = (const float*)d_in[9];
  const float* bs  = (const float*)d_in[10];
  const float* Wf  = (const float*)d_in[11];
  const float* bfp = (const float*)d_in[12];
  const float* W1  = (const float*)d_in[13];
  const float* b1  = (const float*)d_in[14];
  const float* W2  = (const float*)d_in[15];
  const float* b2  = (const float*)d_in[16];
  const float* g1  = (const float*)d_in[17];
  const float* be1 = (const float*)d_in[18];
  const float* g2  = (const float*)d_in[19];
  const float* be2 = (const float*)d_in[20];

  char* ws = (char*)d_ws;
  __bf16* Cbuf  = (__bf16*)(ws + OFF_C);
  __bf16* xn    = (__bf16*)(ws + OFF_XN);
  __bf16* VTb   = (__bf16*)(ws + OFF_VT);
  float*  qdotb = (float*)(ws + OFF_QDOT);
  __bf16* Wcat  = (__bf16*)(ws + OFF_WCAT);
  float*  bcat  = (float*)(ws + OFF_BCAT);
  __bf16* WfT   = (__bf16*)(ws + OFF_WFT);
  __bf16* W1T   = (__bf16*)(ws + OFF_W1T);
  __bf16* W2T   = (__bf16*)(ws + OFF_W2T);
  __bf16* attno = (__bf16*)(ws + OFF_ATTNO);
  __bf16* out1  = (__bf16*)(ws + OFF_OUT1);
  __bf16* onb   = (__bf16*)(ws + OFF_ON);
  __bf16* h1    = (__bf16*)(ws + OFF_H1);
  float*  outp  = (float*)d_out;
  float*  prevp = outp + 6291456;   // 4*2048*768

  k_ln<float><<<2048, 256, 0, stream>>>(x, g1, be1, xn);
  k_packall<<<2352, 256, 0, stream>>>(Wq, Wk, Wv, Wqv, bq, bk, bv, bqv,
                                      Wf, W1, W2, Wcat, bcat, WfT, W1T, W2T);

  k_gemm<768, 0><<<dim3(64, 19), 256, 0, stream>>>(xn, Wcat, bcat, nullptr, nullptr, Cbuf, NC);

  k_vt<<<1024, 256, 0, stream>>>(Cbuf, Ws, bs, VTb, qdotb);

  k_attn<<<768, 512, 0, stream>>>(Cbuf, VTb, Ws, qdotb, attno, prevp);

  k_gemm64<768, 1><<<dim3(128, 6), 256, 0, stream>>>(attno, WfT, bfp, x, nullptr, out1, 768);
  k_ln<__bf16><<<2048, 256, 0, stream>>>(out1, g2, be2, onb);
  k_gemm<768, 2><<<dim3(64, 12), 256, 0, stream>>>(onb, W1T, b1, nullptr, nullptr, h1, 1536);
  k_gemm64<1536, 3><<<dim3(128, 6), 256, 0, stream>>>(h1, W2T, b2, nullptr, out1, outp, 768);
}